// Round 11
// baseline (341.718 us; speedup 1.0000x reference)
//
#include <hip/hip_runtime.h>
#include <hip/hip_fp16.h>

#define D_FEAT 128

constexpr int SCAN_BLOCK = 256;
constexpr int SCAN_ITEMS = 8;
constexpr int SCAN_CHUNK = SCAN_BLOCK * SCAN_ITEMS;

constexpr int BUCKET_SHIFT = 6;      // 64 rows per bucket
constexpr int TILE_ROWS = 1 << BUCKET_SHIFT;
constexpr int NB_MAX = 2048;
constexpr int PART_TILE = 4096;      // edges per partition block (782 blocks @ 3.2M)
constexpr int CAP = 3072;            // staged edges per batch (24 KB LDS)

// ---------------- fallback (round-1) atomic kernel ----------------
__global__ void __launch_bounds__(256) spmm_atomic_kernel(
    const int* __restrict__ row, const int* __restrict__ col,
    const float* __restrict__ vals, const float* __restrict__ embeds,
    float* __restrict__ out, int n_edges)
{
    const int lane = threadIdx.x & 63;
    const int wave_in_block = threadIdx.x >> 6;
    const int waves_per_block = blockDim.x >> 6;
    const int n_waves = gridDim.x * waves_per_block;
    for (int e = blockIdx.x * waves_per_block + wave_in_block; e < n_edges; e += n_waves) {
        const int r = row[e];
        const int c = col[e];
        const float v = vals[e];
        const float2 emb = *reinterpret_cast<const float2*>(&embeds[(size_t)c * D_FEAT + lane * 2]);
        float* o = &out[(size_t)r * D_FEAT + lane * 2];
        atomicAdd(o, emb.x * v);
        atomicAdd(o + 1, emb.y * v);
    }
}

// ================= fast path =================

// LDS-privatized bucket histogram (scanned mode only)
__global__ void __launch_bounds__(256) bucket_hist_kernel(
    const int* __restrict__ row, int* __restrict__ bucket_counts, int n_edges, int nb)
{
    __shared__ int cnt[NB_MAX];
    for (int b = threadIdx.x; b < nb; b += 256) cnt[b] = 0;
    __syncthreads();
    const int i = blockIdx.x * blockDim.x + threadIdx.x;
    const int stride = gridDim.x * blockDim.x;
    const int n4 = n_edges >> 2;
    for (int k = i; k < n4; k += stride) {
        int4 r4 = reinterpret_cast<const int4*>(row)[k];
        atomicAdd(&cnt[r4.x >> BUCKET_SHIFT], 1);
        atomicAdd(&cnt[r4.y >> BUCKET_SHIFT], 1);
        atomicAdd(&cnt[r4.z >> BUCKET_SHIFT], 1);
        atomicAdd(&cnt[r4.w >> BUCKET_SHIFT], 1);
    }
    for (int k = (n4 << 2) + i; k < n_edges; k += stride)
        atomicAdd(&cnt[row[k] >> BUCKET_SHIFT], 1);
    __syncthreads();
    for (int b = threadIdx.x; b < nb; b += 256) {
        int c = cnt[b];
        if (c) atomicAdd(&bucket_counts[b], c);
    }
}

// scanned mode: one block scans bucket counts (2 elems/thread, nb <= 2047)
__global__ void __launch_bounds__(1024) bucket_scan_kernel(
    const int* __restrict__ bucket_counts, int* __restrict__ bucket_ptr,
    int* __restrict__ bucket_fill, int nb)
{
    __shared__ int lds[1024];
    const int t = threadIdx.x;
    int c0 = (2 * t     < nb) ? bucket_counts[2 * t]     : 0;
    int c1 = (2 * t + 1 < nb) ? bucket_counts[2 * t + 1] : 0;
    lds[t] = c0 + c1;
    __syncthreads();
    for (int off = 1; off < 1024; off <<= 1) {
        int x = (t >= off) ? lds[t - off] : 0;
        __syncthreads();
        lds[t] += x;
        __syncthreads();
    }
    const int excl = lds[t] - c0 - c1;
    if (2 * t < nb)     { bucket_ptr[2 * t]     = excl;      bucket_fill[2 * t]     = excl; }
    if (2 * t + 1 < nb) { bucket_ptr[2 * t + 1] = excl + c0; bucket_fill[2 * t + 1] = excl + c0; }
    if (t == 1023) bucket_ptr[nb] = lds[1023];
}

// padded mode: fixed-stride bucket bases, no hist/scan needed
__global__ void __launch_bounds__(256) bucket_init_padded_kernel(
    int* __restrict__ bucket_ptr, int* __restrict__ bucket_fill, int nb, int cap_b)
{
    int b = blockIdx.x * blockDim.x + threadIdx.x;
    if (b < nb) {
        bucket_ptr[b]  = b * cap_b;
        bucket_fill[b] = b * cap_b;
    }
}

// partition edges into 64-row buckets; payload (row_local<<17 | col, half2{v,v})
__global__ void __launch_bounds__(256) partition_kernel(
    const int* __restrict__ row, const int* __restrict__ col, const float* __restrict__ vals,
    int* __restrict__ bucket_fill, uint2* __restrict__ tmp, int n_edges, int nb)
{
    __shared__ int cnt[NB_MAX];
    __shared__ int start[NB_MAX];
    const int tid = threadIdx.x;
    const int base = blockIdx.x * PART_TILE;

    for (int b = tid; b < nb; b += 256) cnt[b] = 0;
    __syncthreads();

    // count pass, int4-vectorized (PART_TILE multiple of 1024)
    #pragma unroll
    for (int k = 0; k < PART_TILE / 1024; ++k) {
        int idx = (base >> 2) + k * 256 + tid;          // int4 index
        if (idx * 4 + 3 < n_edges) {
            int4 r4 = reinterpret_cast<const int4*>(row)[idx];
            atomicAdd(&cnt[r4.x >> BUCKET_SHIFT], 1);
            atomicAdd(&cnt[r4.y >> BUCKET_SHIFT], 1);
            atomicAdd(&cnt[r4.z >> BUCKET_SHIFT], 1);
            atomicAdd(&cnt[r4.w >> BUCKET_SHIFT], 1);
        } else {
            for (int j = 0; j < 4; ++j) {
                int e = idx * 4 + j;
                if (e < n_edges) atomicAdd(&cnt[row[e] >> BUCKET_SHIFT], 1);
            }
        }
    }
    __syncthreads();

    for (int b = tid; b < nb; b += 256) {
        int c = cnt[b];
        if (c > 0) start[b] = atomicAdd(&bucket_fill[b], c);
    }
    __syncthreads();

    // scatter pass, int4/float4-vectorized
    #pragma unroll
    for (int k = 0; k < PART_TILE / 1024; ++k) {
        int idx = (base >> 2) + k * 256 + tid;
        if (idx * 4 + 3 < n_edges) {
            int4  r4 = reinterpret_cast<const int4*>(row)[idx];
            int4  c4 = reinterpret_cast<const int4*>(col)[idx];
            float4 v4 = reinterpret_cast<const float4*>(vals)[idx];
            const int rs[4]   = {r4.x, r4.y, r4.z, r4.w};
            const int cs[4]   = {c4.x, c4.y, c4.z, c4.w};
            const float vs[4] = {v4.x, v4.y, v4.z, v4.w};
            #pragma unroll
            for (int j = 0; j < 4; ++j) {
                int r = rs[j];
                int b = r >> BUCKET_SHIFT;
                int slot = atomicSub(&cnt[b], 1) - 1;
                unsigned hb = (unsigned)__half_as_ushort(__float2half(vs[j]));
                uint2 p;
                p.x = ((unsigned)(r & (TILE_ROWS - 1)) << 17) | (unsigned)cs[j];
                p.y = hb | (hb << 16);
                tmp[start[b] + slot] = p;
            }
        } else {
            for (int j = 0; j < 4; ++j) {
                int e = idx * 4 + j;
                if (e < n_edges) {
                    int r = row[e];
                    int b = r >> BUCKET_SHIFT;
                    int slot = atomicSub(&cnt[b], 1) - 1;
                    unsigned hb = (unsigned)__half_as_ushort(__float2half(vals[e]));
                    uint2 p;
                    p.x = ((unsigned)(r & (TILE_ROWS - 1)) << 17) | (unsigned)col[e];
                    p.y = hb | (hb << 16);
                    tmp[start[b] + slot] = p;
                }
            }
        }
    }
}

// ---------------- embeds f32 -> f16 ----------------
__global__ void __launch_bounds__(256) convert_kernel(
    const float* __restrict__ embeds, unsigned short* __restrict__ out16, int n4)
{
    int i = blockIdx.x * blockDim.x + threadIdx.x;
    int stride = gridDim.x * blockDim.x;
    for (; i < n4; i += stride) {
        float4 f = *reinterpret_cast<const float4*>(&embeds[(size_t)i * 4]);
        ushort4 o;
        o.x = __half_as_ushort(__float2half(f.x));
        o.y = __half_as_ushort(__float2half(f.y));
        o.z = __half_as_ushort(__float2half(f.z));
        o.w = __half_as_ushort(__float2half(f.w));
        *reinterpret_cast<ushort4*>(&out16[(size_t)i * 4]) = o;
    }
}

__device__ __forceinline__ __half2 u2h2(unsigned u)
{
    return *reinterpret_cast<__half2*>(&u);
}

// ---------------- fused sort+SpMM, persistent blocks + dynamic bucket queue ----
// 512 threads (8 waves) per block; one 64-row bucket at a time from a global
// atomic queue (no scheduling tail). Wave owns 8 rows. Quarter-wave gather:
// lanes split into 4 quarters of 16; quarter q handles edges js+q, js+q+4, ...
// each lane loads dwordx4 (8 f16 feats) -> one VMEM instruction per 4 edges.
// Quarters merged via shfl_xor(16,32) at bucket end.
__global__ void __launch_bounds__(512, 6) spmm_bucket_q_kernel(
    const uint2* __restrict__ tmp, const int* __restrict__ bucket_ptr,
    const int* __restrict__ bucket_fill, int* __restrict__ qcounter,
    const unsigned short* __restrict__ embeds16, float* __restrict__ out,
    int n_nodes, int nb)
{
    __shared__ uint2 sedge[CAP];          // 24 KB
    __shared__ int cnt[TILE_ROWS];
    __shared__ int rstart[TILE_ROWS];
    __shared__ int rcur[TILE_ROWS];
    __shared__ int sbucket;

    const int t = threadIdx.x;
    const int lane = t & 63;
    const int q = lane >> 4;              // quarter 0..3
    const int lq = lane & 15;             // lane in quarter; owns feats lq*8..+7
    const int w = t >> 6;                 // wave 0..7, owns rows 8w..8w+7

    for (;;) {
        if (t == 0) sbucket = atomicAdd(qcounter, 1);
        __syncthreads();
        const int b = sbucket;
        if (b >= nb) break;
        const int lo = bucket_ptr[b];
        const int hi = bucket_fill[b];    // final fill = base + count (both modes)

        __half2 acc[32];                  // 8 rows x 4 half2 (8 feats per lane)
        #pragma unroll
        for (int i = 0; i < 32; ++i) acc[i] = __float2half2_rn(0.f);

        for (int cur = lo; cur < hi; cur += CAP) {
            const int bcount = min(CAP, hi - cur);

            if (t < TILE_ROWS) cnt[t] = 0;
            __syncthreads();

            // count pass (tmp is L2-hot; no register staging -> low VGPR)
            for (int idx = t; idx < bcount; idx += 512)
                atomicAdd(&cnt[(tmp[cur + idx].x >> 17) & (TILE_ROWS - 1)], 1);
            __syncthreads();

            // wave 0: 64-wide exclusive scan via shfl_up (2 barriers total)
            if (w == 0) {
                int v = cnt[lane];
                int inc = v;
                #pragma unroll
                for (int off = 1; off < 64; off <<= 1) {
                    int x = __shfl_up(inc, off);
                    if (lane >= off) inc += x;
                }
                rstart[lane] = inc - v;
                rcur[lane] = 0;
            }
            __syncthreads();

            // scatter row-sorted into sedge
            for (int idx = t; idx < bcount; idx += 512) {
                uint2 p = tmp[cur + idx];
                int rl = (p.x >> 17) & (TILE_ROWS - 1);
                int pos = rstart[rl] + atomicAdd(&rcur[rl], 1);
                sedge[pos] = uint2{p.x & 0x1FFFFu, p.y};
            }
            __syncthreads();

            // consume: wave w rows 8w..8w+7; quarter q strides 4, unroll 2
            #pragma unroll
            for (int rr = 0; rr < 8; ++rr) {
                const int r = w * 8 + rr;
                const int js = rstart[r];
                const int je = js + cnt[r];
                int j = js + q;
                for (; j + 4 < je; j += 8) {
                    uint2 e0 = sedge[j];
                    uint2 e1 = sedge[j + 4];
                    uint4 u0 = *reinterpret_cast<const uint4*>(&embeds16[((size_t)e0.x << 7) + lq * 8]);
                    uint4 u1 = *reinterpret_cast<const uint4*>(&embeds16[((size_t)e1.x << 7) + lq * 8]);
                    const __half2 v0 = u2h2(e0.y);
                    const __half2 v1 = u2h2(e1.y);
                    acc[4*rr+0] = __hfma2(v0, u2h2(u0.x), acc[4*rr+0]);
                    acc[4*rr+1] = __hfma2(v0, u2h2(u0.y), acc[4*rr+1]);
                    acc[4*rr+2] = __hfma2(v0, u2h2(u0.z), acc[4*rr+2]);
                    acc[4*rr+3] = __hfma2(v0, u2h2(u0.w), acc[4*rr+3]);
                    acc[4*rr+0] = __hfma2(v1, u2h2(u1.x), acc[4*rr+0]);
                    acc[4*rr+1] = __hfma2(v1, u2h2(u1.y), acc[4*rr+1]);
                    acc[4*rr+2] = __hfma2(v1, u2h2(u1.z), acc[4*rr+2]);
                    acc[4*rr+3] = __hfma2(v1, u2h2(u1.w), acc[4*rr+3]);
                }
                if (j < je) {
                    uint2 e0 = sedge[j];
                    uint4 u0 = *reinterpret_cast<const uint4*>(&embeds16[((size_t)e0.x << 7) + lq * 8]);
                    const __half2 v0 = u2h2(e0.y);
                    acc[4*rr+0] = __hfma2(v0, u2h2(u0.x), acc[4*rr+0]);
                    acc[4*rr+1] = __hfma2(v0, u2h2(u0.y), acc[4*rr+1]);
                    acc[4*rr+2] = __hfma2(v0, u2h2(u0.z), acc[4*rr+2]);
                    acc[4*rr+3] = __hfma2(v0, u2h2(u0.w), acc[4*rr+3]);
                }
            }
            __syncthreads();   // protect sedge/cnt before next batch
        }

        // merge quarters in f32 (shfl_xor 16 then 32), quarter q writes
        // rows w*8+q and w*8+4+q (static acc indices, predicated select)
        float4 oa0, oa1, ob0, ob1;
        oa0 = oa1 = ob0 = ob1 = float4{0.f, 0.f, 0.f, 0.f};
        #pragma unroll
        for (int rr = 0; rr < 8; ++rr) {
            float2 f0 = __half22float2(acc[4*rr+0]);
            float2 f1 = __half22float2(acc[4*rr+1]);
            float2 f2 = __half22float2(acc[4*rr+2]);
            float2 f3 = __half22float2(acc[4*rr+3]);
            float v0 = f0.x, v1 = f0.y, v2 = f1.x, v3 = f1.y;
            float v4 = f2.x, v5 = f2.y, v6 = f3.x, v7 = f3.y;
            v0 += __shfl_xor(v0, 16); v0 += __shfl_xor(v0, 32);
            v1 += __shfl_xor(v1, 16); v1 += __shfl_xor(v1, 32);
            v2 += __shfl_xor(v2, 16); v2 += __shfl_xor(v2, 32);
            v3 += __shfl_xor(v3, 16); v3 += __shfl_xor(v3, 32);
            v4 += __shfl_xor(v4, 16); v4 += __shfl_xor(v4, 32);
            v5 += __shfl_xor(v5, 16); v5 += __shfl_xor(v5, 32);
            v6 += __shfl_xor(v6, 16); v6 += __shfl_xor(v6, 32);
            v7 += __shfl_xor(v7, 16); v7 += __shfl_xor(v7, 32);
            if (rr == q)     { oa0 = float4{v0,v1,v2,v3}; oa1 = float4{v4,v5,v6,v7}; }
            if (rr == q + 4) { ob0 = float4{v0,v1,v2,v3}; ob1 = float4{v4,v5,v6,v7}; }
        }
        const int rbase = b << BUCKET_SHIFT;
        const int rA = rbase + w * 8 + q;
        const int rB = rA + 4;
        if (rA < n_nodes) {
            *reinterpret_cast<float4*>(&out[(size_t)rA * D_FEAT + lq * 8])     = oa0;
            *reinterpret_cast<float4*>(&out[(size_t)rA * D_FEAT + lq * 8 + 4]) = oa1;
        }
        if (rB < n_nodes) {
            *reinterpret_cast<float4*>(&out[(size_t)rB * D_FEAT + lq * 8])     = ob0;
            *reinterpret_cast<float4*>(&out[(size_t)rB * D_FEAT + lq * 8 + 4]) = ob1;
        }
        __syncthreads();   // protect sbucket before next grab
    }
}

// ================= round-2 fallback pieces =================
__global__ void hist_kernel(const int* __restrict__ row, int* __restrict__ counts, int n)
{
    int i = blockIdx.x * blockDim.x + threadIdx.x;
    int stride = gridDim.x * blockDim.x;
    for (; i < n; i += stride) atomicAdd(&counts[row[i]], 1);
}

__global__ void __launch_bounds__(SCAN_BLOCK) scan1_kernel(
    const int* __restrict__ counts, int* __restrict__ scan_out,
    int* __restrict__ chunk_sums, int n)
{
    __shared__ int lds[SCAN_BLOCK];
    const int chunk = blockIdx.x;
    const int base = chunk * SCAN_CHUNK;
    const int tbase = base + threadIdx.x * SCAN_ITEMS;

    int pref[SCAN_ITEMS];
    int tsum = 0;
    for (int k = 0; k < SCAN_ITEMS; ++k) {
        int idx = tbase + k;
        int v = (idx < n) ? counts[idx] : 0;
        pref[k] = tsum;
        tsum += v;
    }
    lds[threadIdx.x] = tsum;
    __syncthreads();
    for (int off = 1; off < SCAN_BLOCK; off <<= 1) {
        int v = (threadIdx.x >= off) ? lds[threadIdx.x - off] : 0;
        __syncthreads();
        lds[threadIdx.x] += v;
        __syncthreads();
    }
    const int texcl = (threadIdx.x == 0) ? 0 : lds[threadIdx.x - 1];
    for (int k = 0; k < SCAN_ITEMS; ++k) {
        int idx = tbase + k;
        if (idx < n) scan_out[idx] = texcl + pref[k];
    }
    if (threadIdx.x == SCAN_BLOCK - 1) chunk_sums[chunk] = lds[SCAN_BLOCK - 1];
}

__global__ void scan2_kernel(int* chunk_sums, int nchunks)
{
    if (blockIdx.x == 0 && threadIdx.x == 0) {
        int acc = 0;
        for (int i = 0; i < nchunks; ++i) { int v = chunk_sums[i]; chunk_sums[i] = acc; acc += v; }
    }
}

__global__ void scan3_kernel(int* __restrict__ row_ptr, const int* __restrict__ chunk_sums,
                             int n, int n_edges)
{
    int i = blockIdx.x * blockDim.x + threadIdx.x;
    if (i < n) row_ptr[i] += chunk_sums[i / SCAN_CHUNK];
    if (i == 0) row_ptr[n] = n_edges;
}

__global__ void scatter_kernel(const int* __restrict__ row, const int* __restrict__ col,
                               const float* __restrict__ vals,
                               const int* __restrict__ row_ptr, int* __restrict__ row_fill,
                               uint2* __restrict__ sorted_cv, int n_edges)
{
    int i = blockIdx.x * blockDim.x + threadIdx.x;
    int stride = gridDim.x * blockDim.x;
    for (; i < n_edges; i += stride) {
        int r = row[i];
        int pos = row_ptr[r] + atomicAdd(&row_fill[r], 1);
        uint2 cv;
        cv.x = (unsigned)col[i];
        cv.y = __float_as_uint(vals[i]);
        sorted_cv[pos] = cv;
    }
}

__global__ void __launch_bounds__(256) spmm_csr_kernel(
    const int* __restrict__ row_ptr, const uint2* __restrict__ sorted_cv,
    const float* __restrict__ embeds, float* __restrict__ out, int n_rows)
{
    const int lane = threadIdx.x & 63;
    const int wid = (blockIdx.x * blockDim.x + threadIdx.x) >> 6;
    const int n_waves = (gridDim.x * blockDim.x) >> 6;

    for (int r = wid; r < n_rows; r += n_waves) {
        const int start = row_ptr[r];
        const int end   = row_ptr[r + 1];
        float2 acc = {0.f, 0.f};
        for (int j = start; j < end; ++j) {
            uint2 cv = sorted_cv[j];
            const float2 e = *reinterpret_cast<const float2*>(&embeds[(size_t)cv.x * D_FEAT + lane * 2]);
            const float v = __uint_as_float(cv.y);
            acc.x += v * e.x;
            acc.y += v * e.y;
        }
        *reinterpret_cast<float2*>(&out[(size_t)r * D_FEAT + lane * 2]) = acc;
    }
}

extern "C" void kernel_launch(void* const* d_in, const int* in_sizes, int n_in,
                              void* d_out, int out_size, void* d_ws, size_t ws_size,
                              hipStream_t stream) {
    const int*   row    = (const int*)d_in[0];
    const int*   col    = (const int*)d_in[1];
    const float* vals   = (const float*)d_in[2];
    const float* embeds = (const float*)d_in[3];
    float*       out    = (float*)d_out;

    const int n_edges = in_sizes[0];
    const int n_nodes = in_sizes[3] / D_FEAT;
    const int nchunks = (n_nodes + SCAN_CHUNK - 1) / SCAN_CHUNK;
    const int nb = (n_nodes + TILE_ROWS - 1) >> BUCKET_SHIFT;

    // padded bucket stride: avg + 25% + 256 (>=16 sigma for Binomial bucket sizes)
    const int avg = n_edges / (nb > 0 ? nb : 1);
    const int cap_b = avg + avg / 4 + 256;

    char* base = (char*)d_ws;

    // padded layout (no hist/scan)
    size_t offP = 0;
    uint2* tmpP           = (uint2*)(base + offP);             offP += ((size_t)nb * cap_b * 8 + 255) & ~(size_t)255;
    unsigned short* emb16P = (unsigned short*)(base + offP);   offP += ((size_t)n_nodes * D_FEAT * 2 + 255) & ~(size_t)255;
    int* bptrP            = (int*)(base + offP);               offP += (size_t)(nb + 1) * 4;
    int* bfillP           = (int*)(base + offP);               offP += (size_t)(nb + 1) * 4;
    int* qcntP            = (int*)(base + offP);               offP += 256;

    // scanned layout (exact tmp)
    size_t offS = 0;
    uint2* tmpS           = (uint2*)(base + offS);             offS += ((size_t)n_edges * 8 + 255) & ~(size_t)255;
    unsigned short* emb16S = (unsigned short*)(base + offS);   offS += ((size_t)n_nodes * D_FEAT * 2 + 255) & ~(size_t)255;
    int* bcntS            = (int*)(base + offS);               offS += (size_t)(nb + 1) * 4;
    int* bptrS            = (int*)(base + offS);               offS += (size_t)(nb + 1) * 4;
    int* bfillS           = (int*)(base + offS);               offS += (size_t)(nb + 1) * 4;
    int* qcntS            = (int*)(base + offS);               offS += 256;

    const bool common_ok = (nb <= 2047) && (n_nodes < (1 << 17));
    const bool padded_ok  = common_ok && (offP <= ws_size);
    const bool scanned_ok = common_ok && (offS <= ws_size);

    if (!padded_ok && !scanned_ok) {
        // round-2 fallback layout
        size_t off2 = 0;
        uint2* s_cv = (uint2*)(base + off2); off2 += (size_t)n_edges * 8;
        int* rc  = (int*)(base + off2); off2 += (size_t)n_nodes * 4;
        int* rf  = (int*)(base + off2); off2 += (size_t)n_nodes * 4;
        int* rp  = (int*)(base + off2); off2 += (size_t)(n_nodes + 1) * 4;
        int* cs  = (int*)(base + off2); off2 += (size_t)nchunks * 4;
        if (off2 > ws_size) {
            hipMemsetAsync(d_out, 0, (size_t)out_size * sizeof(float), stream);
            spmm_atomic_kernel<<<2048, 256, 0, stream>>>(row, col, vals, embeds, out, n_edges);
            return;
        }
        hipMemsetAsync(rc, 0, (size_t)n_nodes * 2 * sizeof(int), stream);
        hist_kernel<<<2048, 256, 0, stream>>>(row, rc, n_edges);
        scan1_kernel<<<nchunks, SCAN_BLOCK, 0, stream>>>(rc, rp, cs, n_nodes);
        scan2_kernel<<<1, 64, 0, stream>>>(cs, nchunks);
        scan3_kernel<<<(n_nodes + 256) / 256, 256, 0, stream>>>(rp, cs, n_nodes, n_edges);
        scatter_kernel<<<2048, 256, 0, stream>>>(row, col, vals, rp, rf, s_cv, n_edges);
        spmm_csr_kernel<<<4096, 256, 0, stream>>>(rp, s_cv, embeds, out, n_nodes);
        return;
    }

    uint2* tmp;
    unsigned short* embeds16;
    int *bptr, *bfill, *qcnt;

    const int part_blocks = (n_edges + PART_TILE - 1) / PART_TILE;

    if (padded_ok) {
        tmp = tmpP; embeds16 = emb16P; bptr = bptrP; bfill = bfillP; qcnt = qcntP;
        bucket_init_padded_kernel<<<(nb + 255) / 256, 256, 0, stream>>>(bptr, bfill, nb, cap_b);
    } else {
        tmp = tmpS; embeds16 = emb16S; bptr = bptrS; bfill = bfillS; qcnt = qcntS;
        hipMemsetAsync(bcntS, 0, (size_t)(nb + 1) * sizeof(int), stream);
        bucket_hist_kernel<<<512, 256, 0, stream>>>(row, bcntS, n_edges, nb);
        bucket_scan_kernel<<<1, 1024, 0, stream>>>(bcntS, bptr, bfill, nb);
    }
    hipMemsetAsync(qcnt, 0, sizeof(int), stream);

    partition_kernel<<<part_blocks, 256, 0, stream>>>(row, col, vals, bfill, tmp, n_edges, nb);

    const int n4 = n_nodes * D_FEAT / 4;
    convert_kernel<<<4096, 256, 0, stream>>>(embeds, embeds16, n4);

    // persistent blocks + dynamic queue: launch max-residency grid
    spmm_bucket_q_kernel<<<1024, 512, 0, stream>>>(tmp, bptr, bfill, qcnt,
                                                   embeds16, out, n_nodes, nb);
}

// Round 12
// 281.084 us; speedup vs baseline: 1.2157x; 1.2157x over previous
//
#include <hip/hip_runtime.h>
#include <hip/hip_fp16.h>

#define D_FEAT 128

constexpr int SCAN_BLOCK = 256;
constexpr int SCAN_ITEMS = 8;
constexpr int SCAN_CHUNK = SCAN_BLOCK * SCAN_ITEMS;

constexpr int BUCKET_SHIFT = 7;      // 128 rows per bucket (round-10 proven shape)
constexpr int TILE_ROWS = 1 << BUCKET_SHIFT;
constexpr int NB_MAX = 1024;
constexpr int PART_TILE = 4096;      // 782 partition blocks @ 3.2M edges
constexpr int CAP = 6144;            // staged edges per batch (48 KB LDS)

// ---------------- fallback (round-1) atomic kernel ----------------
__global__ void __launch_bounds__(256) spmm_atomic_kernel(
    const int* __restrict__ row, const int* __restrict__ col,
    const float* __restrict__ vals, const float* __restrict__ embeds,
    float* __restrict__ out, int n_edges)
{
    const int lane = threadIdx.x & 63;
    const int wave_in_block = threadIdx.x >> 6;
    const int waves_per_block = blockDim.x >> 6;
    const int n_waves = gridDim.x * waves_per_block;
    for (int e = blockIdx.x * waves_per_block + wave_in_block; e < n_edges; e += n_waves) {
        const int r = row[e];
        const int c = col[e];
        const float v = vals[e];
        const float2 emb = *reinterpret_cast<const float2*>(&embeds[(size_t)c * D_FEAT + lane * 2]);
        float* o = &out[(size_t)r * D_FEAT + lane * 2];
        atomicAdd(o, emb.x * v);
        atomicAdd(o + 1, emb.y * v);
    }
}

// ================= fast path =================

// LDS-privatized bucket histogram (scanned mode only)
__global__ void __launch_bounds__(256) bucket_hist_kernel(
    const int* __restrict__ row, int* __restrict__ bucket_counts, int n_edges, int nb)
{
    __shared__ int cnt[NB_MAX];
    for (int b = threadIdx.x; b < nb; b += 256) cnt[b] = 0;
    __syncthreads();
    const int i = blockIdx.x * blockDim.x + threadIdx.x;
    const int stride = gridDim.x * blockDim.x;
    const int n4 = n_edges >> 2;
    for (int k = i; k < n4; k += stride) {
        int4 r4 = reinterpret_cast<const int4*>(row)[k];
        atomicAdd(&cnt[r4.x >> BUCKET_SHIFT], 1);
        atomicAdd(&cnt[r4.y >> BUCKET_SHIFT], 1);
        atomicAdd(&cnt[r4.z >> BUCKET_SHIFT], 1);
        atomicAdd(&cnt[r4.w >> BUCKET_SHIFT], 1);
    }
    for (int k = (n4 << 2) + i; k < n_edges; k += stride)
        atomicAdd(&cnt[row[k] >> BUCKET_SHIFT], 1);
    __syncthreads();
    for (int b = threadIdx.x; b < nb; b += 256) {
        int c = cnt[b];
        if (c) atomicAdd(&bucket_counts[b], c);
    }
}

// scanned mode: one block scans bucket counts -> bucket_ptr (excl) + bucket_fill
__global__ void __launch_bounds__(1024) bucket_scan_kernel(
    const int* __restrict__ bucket_counts, int* __restrict__ bucket_ptr,
    int* __restrict__ bucket_fill, int nb)
{
    __shared__ int lds[1024];
    const int t = threadIdx.x;
    lds[t] = (t < nb) ? bucket_counts[t] : 0;
    __syncthreads();
    for (int off = 1; off < 1024; off <<= 1) {
        int x = (t >= off) ? lds[t - off] : 0;
        __syncthreads();
        lds[t] += x;
        __syncthreads();
    }
    const int excl = (t == 0) ? 0 : lds[t - 1];
    if (t <= nb) bucket_ptr[t] = excl;
    if (t < nb)  bucket_fill[t] = excl;
}

// padded mode: fixed-stride bucket bases, no hist/scan needed
__global__ void __launch_bounds__(256) bucket_init_padded_kernel(
    int* __restrict__ bucket_ptr, int* __restrict__ bucket_fill, int nb, int cap_b)
{
    int b = blockIdx.x * blockDim.x + threadIdx.x;
    if (b < nb) {
        bucket_ptr[b]  = b * cap_b;
        bucket_fill[b] = b * cap_b;
    }
}

// partition edges into 128-row buckets; payload (row_local<<17 | col, half2{v,v})
__global__ void __launch_bounds__(256) partition_kernel(
    const int* __restrict__ row, const int* __restrict__ col, const float* __restrict__ vals,
    int* __restrict__ bucket_fill, uint2* __restrict__ tmp, int n_edges, int nb)
{
    __shared__ int cnt[NB_MAX];
    __shared__ int start[NB_MAX];
    const int tid = threadIdx.x;
    const int base = blockIdx.x * PART_TILE;

    for (int b = tid; b < NB_MAX; b += 256) cnt[b] = 0;
    __syncthreads();

    // count pass, int4-vectorized (PART_TILE multiple of 1024)
    #pragma unroll
    for (int k = 0; k < PART_TILE / 1024; ++k) {
        int idx = (base >> 2) + k * 256 + tid;          // int4 index
        if (idx * 4 + 3 < n_edges) {
            int4 r4 = reinterpret_cast<const int4*>(row)[idx];
            atomicAdd(&cnt[r4.x >> BUCKET_SHIFT], 1);
            atomicAdd(&cnt[r4.y >> BUCKET_SHIFT], 1);
            atomicAdd(&cnt[r4.z >> BUCKET_SHIFT], 1);
            atomicAdd(&cnt[r4.w >> BUCKET_SHIFT], 1);
        } else {
            for (int j = 0; j < 4; ++j) {
                int e = idx * 4 + j;
                if (e < n_edges) atomicAdd(&cnt[row[e] >> BUCKET_SHIFT], 1);
            }
        }
    }
    __syncthreads();

    for (int b = tid; b < nb; b += 256) {
        int c = cnt[b];
        if (c > 0) start[b] = atomicAdd(&bucket_fill[b], c);
    }
    __syncthreads();

    // scatter pass, int4/float4-vectorized
    #pragma unroll
    for (int k = 0; k < PART_TILE / 1024; ++k) {
        int idx = (base >> 2) + k * 256 + tid;
        if (idx * 4 + 3 < n_edges) {
            int4  r4 = reinterpret_cast<const int4*>(row)[idx];
            int4  c4 = reinterpret_cast<const int4*>(col)[idx];
            float4 v4 = reinterpret_cast<const float4*>(vals)[idx];
            const int rs[4]   = {r4.x, r4.y, r4.z, r4.w};
            const int cs[4]   = {c4.x, c4.y, c4.z, c4.w};
            const float vs[4] = {v4.x, v4.y, v4.z, v4.w};
            #pragma unroll
            for (int j = 0; j < 4; ++j) {
                int r = rs[j];
                int b = r >> BUCKET_SHIFT;
                int slot = atomicSub(&cnt[b], 1) - 1;
                unsigned hb = (unsigned)__half_as_ushort(__float2half(vs[j]));
                uint2 p;
                p.x = ((unsigned)(r & (TILE_ROWS - 1)) << 17) | (unsigned)cs[j];
                p.y = hb | (hb << 16);
                tmp[start[b] + slot] = p;
            }
        } else {
            for (int j = 0; j < 4; ++j) {
                int e = idx * 4 + j;
                if (e < n_edges) {
                    int r = row[e];
                    int b = r >> BUCKET_SHIFT;
                    int slot = atomicSub(&cnt[b], 1) - 1;
                    unsigned hb = (unsigned)__half_as_ushort(__float2half(vals[e]));
                    uint2 p;
                    p.x = ((unsigned)(r & (TILE_ROWS - 1)) << 17) | (unsigned)col[e];
                    p.y = hb | (hb << 16);
                    tmp[start[b] + slot] = p;
                }
            }
        }
    }
}

// ---------------- embeds f32 -> f16 ----------------
__global__ void __launch_bounds__(256) convert_kernel(
    const float* __restrict__ embeds, unsigned short* __restrict__ out16, int n4)
{
    int i = blockIdx.x * blockDim.x + threadIdx.x;
    int stride = gridDim.x * blockDim.x;
    for (; i < n4; i += stride) {
        float4 f = *reinterpret_cast<const float4*>(&embeds[(size_t)i * 4]);
        ushort4 o;
        o.x = __half_as_ushort(__float2half(f.x));
        o.y = __half_as_ushort(__float2half(f.y));
        o.z = __half_as_ushort(__float2half(f.z));
        o.w = __half_as_ushort(__float2half(f.w));
        *reinterpret_cast<ushort4*>(&out16[(size_t)i * 4]) = o;
    }
}

__device__ __forceinline__ __half2 u2h2(unsigned u)
{
    return *reinterpret_cast<__half2*>(&u);
}

// ---------------- fused sort+SpMM: round-10 kernel + persistent bucket queue ----
// 1024 threads / 16 waves; one 128-row bucket at a time from a global atomic
// queue (eliminates the 1.53-round scheduling tail measured in round 10).
// Wave owns 8 rows; lanes 0-31 even edges, 32-63 odd; lane loads dwordx2
// (4 f16 feats); math is v_pk_fma_f16. Halves merged via shfl at bucket end.
__global__ void __launch_bounds__(1024, 8) spmm_bucket_q_kernel(
    const uint2* __restrict__ tmp, const int* __restrict__ bucket_ptr,
    const int* __restrict__ bucket_fill, int* __restrict__ qcounter,
    const unsigned short* __restrict__ embeds16, float* __restrict__ out,
    int n_nodes, int nb)
{
    __shared__ uint2 sedge[CAP];          // 48 KB
    __shared__ int cnt[TILE_ROWS];
    __shared__ int rstart[TILE_ROWS];
    __shared__ int rcur[TILE_ROWS];
    __shared__ int sscan[TILE_ROWS];
    __shared__ int sbucket;

    const int t = threadIdx.x;
    const int lane = t & 63;
    const int h = lane >> 5;              // half-wave id (0/1)
    const int lq = lane & 31;             // lane within half; owns feats lq*4..+3
    const int w = t >> 6;                 // wave 0..15, owns rows 8w..8w+7

    for (;;) {
        if (t == 0) sbucket = atomicAdd(qcounter, 1);
        __syncthreads();
        const int b = sbucket;
        if (b >= nb) break;
        const int lo = bucket_ptr[b];
        const int hi = bucket_fill[b];    // final fill = base + count (both modes)

        __half2 acc[16];                  // [2*rr] = feats lq*4..+1, [2*rr+1] = +2..+3
        #pragma unroll
        for (int i = 0; i < 16; ++i) acc[i] = __float2half2_rn(0.f);

        for (int cur = lo; cur < hi; cur += CAP) {
            const int bcount = min(CAP, hi - cur);

            // stage edges into registers (coalesced), CAP/1024 = 6 per thread
            uint2 e[6];
            #pragma unroll
            for (int k = 0; k < 6; ++k) {
                int idx = t + k * 1024;
                if (idx < bcount) e[k] = tmp[cur + idx];
            }
            if (t < TILE_ROWS) { cnt[t] = 0; rcur[t] = 0; }
            __syncthreads();

            // per-row count (int LDS atomics)
            #pragma unroll
            for (int k = 0; k < 6; ++k) {
                int idx = t + k * 1024;
                if (idx < bcount) atomicAdd(&cnt[(e[k].x >> 17) & (TILE_ROWS - 1)], 1);
            }
            __syncthreads();

            // exclusive scan of cnt[128] -> rstart
            if (t < TILE_ROWS) sscan[t] = cnt[t];
            __syncthreads();
            for (int off = 1; off < TILE_ROWS; off <<= 1) {
                int v = 0;
                if (t < TILE_ROWS && t >= off) v = sscan[t - off];
                __syncthreads();
                if (t < TILE_ROWS) sscan[t] += v;
                __syncthreads();
            }
            if (t < TILE_ROWS) rstart[t] = sscan[t] - cnt[t];
            __syncthreads();

            // scatter row-sorted into sedge
            #pragma unroll
            for (int k = 0; k < 6; ++k) {
                int idx = t + k * 1024;
                if (idx < bcount) {
                    int rl = (e[k].x >> 17) & (TILE_ROWS - 1);
                    int pos = rstart[rl] + atomicAdd(&rcur[rl], 1);
                    sedge[pos] = uint2{e[k].x & 0x1FFFFu, e[k].y};
                }
            }
            __syncthreads();

            // consume: wave w accumulates its 8 rows; halves take alternating edges
            #pragma unroll
            for (int rr = 0; rr < 8; ++rr) {
                const int r = w * 8 + rr;
                const int js = rstart[r];
                const int je = js + cnt[r];
                int j = js;
                for (; j + 7 < je; j += 8) {
                    uint2 q0 = sedge[j + 0 + h];
                    uint2 q1 = sedge[j + 2 + h];
                    uint2 q2 = sedge[j + 4 + h];
                    uint2 q3 = sedge[j + 6 + h];
                    uint2 u0 = *reinterpret_cast<const uint2*>(&embeds16[((size_t)q0.x << 7) + lq * 4]);
                    uint2 u1 = *reinterpret_cast<const uint2*>(&embeds16[((size_t)q1.x << 7) + lq * 4]);
                    uint2 u2 = *reinterpret_cast<const uint2*>(&embeds16[((size_t)q2.x << 7) + lq * 4]);
                    uint2 u3 = *reinterpret_cast<const uint2*>(&embeds16[((size_t)q3.x << 7) + lq * 4]);
                    acc[2*rr]   = __hfma2(u2h2(q0.y), u2h2(u0.x), acc[2*rr]);
                    acc[2*rr+1] = __hfma2(u2h2(q0.y), u2h2(u0.y), acc[2*rr+1]);
                    acc[2*rr]   = __hfma2(u2h2(q1.y), u2h2(u1.x), acc[2*rr]);
                    acc[2*rr+1] = __hfma2(u2h2(q1.y), u2h2(u1.y), acc[2*rr+1]);
                    acc[2*rr]   = __hfma2(u2h2(q2.y), u2h2(u2.x), acc[2*rr]);
                    acc[2*rr+1] = __hfma2(u2h2(q2.y), u2h2(u2.y), acc[2*rr+1]);
                    acc[2*rr]   = __hfma2(u2h2(q3.y), u2h2(u3.x), acc[2*rr]);
                    acc[2*rr+1] = __hfma2(u2h2(q3.y), u2h2(u3.y), acc[2*rr+1]);
                }
                for (; j + 1 < je; j += 2) {
                    uint2 q = sedge[j + h];
                    uint2 u = *reinterpret_cast<const uint2*>(&embeds16[((size_t)q.x << 7) + lq * 4]);
                    acc[2*rr]   = __hfma2(u2h2(q.y), u2h2(u.x), acc[2*rr]);
                    acc[2*rr+1] = __hfma2(u2h2(q.y), u2h2(u.y), acc[2*rr+1]);
                }
                if (j < je && h == 0) {      // single leftover edge: half 0 only
                    uint2 q = sedge[j];
                    uint2 u = *reinterpret_cast<const uint2*>(&embeds16[((size_t)q.x << 7) + lq * 4]);
                    acc[2*rr]   = __hfma2(u2h2(q.y), u2h2(u.x), acc[2*rr]);
                    acc[2*rr+1] = __hfma2(u2h2(q.y), u2h2(u.y), acc[2*rr+1]);
                }
            }
            __syncthreads();   // protect sedge before next batch
        }

        // convert to f32, merge halves (disjoint edge subsets), write
        float4 facc[8];
        #pragma unroll
        for (int rr = 0; rr < 8; ++rr) {
            float2 a = __half22float2(acc[2*rr]);
            float2 bq = __half22float2(acc[2*rr+1]);
            facc[rr] = float4{a.x, a.y, bq.x, bq.y};
            facc[rr].x += __shfl_xor(facc[rr].x, 32);
            facc[rr].y += __shfl_xor(facc[rr].y, 32);
            facc[rr].z += __shfl_xor(facc[rr].z, 32);
            facc[rr].w += __shfl_xor(facc[rr].w, 32);
        }

        // half h writes rows w*8 + k + 4h (static indices + cndmask select)
        const int rbase = b << BUCKET_SHIFT;
        #pragma unroll
        for (int k = 0; k < 4; ++k) {
            float4 a0 = facc[k];
            float4 a1 = facc[k + 4];
            float4 vv;
            vv.x = h ? a1.x : a0.x;
            vv.y = h ? a1.y : a0.y;
            vv.z = h ? a1.z : a0.z;
            vv.w = h ? a1.w : a0.w;
            int r = rbase + w * 8 + k + 4 * h;
            if (r < n_nodes)
                *reinterpret_cast<float4*>(&out[(size_t)r * D_FEAT + lq * 4]) = vv;
        }
        __syncthreads();   // protect sbucket before next grab
    }
}

// ================= round-2 fallback pieces =================
__global__ void hist_kernel(const int* __restrict__ row, int* __restrict__ counts, int n)
{
    int i = blockIdx.x * blockDim.x + threadIdx.x;
    int stride = gridDim.x * blockDim.x;
    for (; i < n; i += stride) atomicAdd(&counts[row[i]], 1);
}

__global__ void __launch_bounds__(SCAN_BLOCK) scan1_kernel(
    const int* __restrict__ counts, int* __restrict__ scan_out,
    int* __restrict__ chunk_sums, int n)
{
    __shared__ int lds[SCAN_BLOCK];
    const int chunk = blockIdx.x;
    const int base = chunk * SCAN_CHUNK;
    const int tbase = base + threadIdx.x * SCAN_ITEMS;

    int pref[SCAN_ITEMS];
    int tsum = 0;
    for (int k = 0; k < SCAN_ITEMS; ++k) {
        int idx = tbase + k;
        int v = (idx < n) ? counts[idx] : 0;
        pref[k] = tsum;
        tsum += v;
    }
    lds[threadIdx.x] = tsum;
    __syncthreads();
    for (int off = 1; off < SCAN_BLOCK; off <<= 1) {
        int v = (threadIdx.x >= off) ? lds[threadIdx.x - off] : 0;
        __syncthreads();
        lds[threadIdx.x] += v;
        __syncthreads();
    }
    const int texcl = (threadIdx.x == 0) ? 0 : lds[threadIdx.x - 1];
    for (int k = 0; k < SCAN_ITEMS; ++k) {
        int idx = tbase + k;
        if (idx < n) scan_out[idx] = texcl + pref[k];
    }
    if (threadIdx.x == SCAN_BLOCK - 1) chunk_sums[chunk] = lds[SCAN_BLOCK - 1];
}

__global__ void scan2_kernel(int* chunk_sums, int nchunks)
{
    if (blockIdx.x == 0 && threadIdx.x == 0) {
        int acc = 0;
        for (int i = 0; i < nchunks; ++i) { int v = chunk_sums[i]; chunk_sums[i] = acc; acc += v; }
    }
}

__global__ void scan3_kernel(int* __restrict__ row_ptr, const int* __restrict__ chunk_sums,
                             int n, int n_edges)
{
    int i = blockIdx.x * blockDim.x + threadIdx.x;
    if (i < n) row_ptr[i] += chunk_sums[i / SCAN_CHUNK];
    if (i == 0) row_ptr[n] = n_edges;
}

__global__ void scatter_kernel(const int* __restrict__ row, const int* __restrict__ col,
                               const float* __restrict__ vals,
                               const int* __restrict__ row_ptr, int* __restrict__ row_fill,
                               uint2* __restrict__ sorted_cv, int n_edges)
{
    int i = blockIdx.x * blockDim.x + threadIdx.x;
    int stride = gridDim.x * blockDim.x;
    for (; i < n_edges; i += stride) {
        int r = row[i];
        int pos = row_ptr[r] + atomicAdd(&row_fill[r], 1);
        uint2 cv;
        cv.x = (unsigned)col[i];
        cv.y = __float_as_uint(vals[i]);
        sorted_cv[pos] = cv;
    }
}

__global__ void __launch_bounds__(256) spmm_csr_kernel(
    const int* __restrict__ row_ptr, const uint2* __restrict__ sorted_cv,
    const float* __restrict__ embeds, float* __restrict__ out, int n_rows)
{
    const int lane = threadIdx.x & 63;
    const int wid = (blockIdx.x * blockDim.x + threadIdx.x) >> 6;
    const int n_waves = (gridDim.x * blockDim.x) >> 6;

    for (int r = wid; r < n_rows; r += n_waves) {
        const int start = row_ptr[r];
        const int end   = row_ptr[r + 1];
        float2 acc = {0.f, 0.f};
        for (int j = start; j < end; ++j) {
            uint2 cv = sorted_cv[j];
            const float2 e = *reinterpret_cast<const float2*>(&embeds[(size_t)cv.x * D_FEAT + lane * 2]);
            const float v = __uint_as_float(cv.y);
            acc.x += v * e.x;
            acc.y += v * e.y;
        }
        *reinterpret_cast<float2*>(&out[(size_t)r * D_FEAT + lane * 2]) = acc;
    }
}

extern "C" void kernel_launch(void* const* d_in, const int* in_sizes, int n_in,
                              void* d_out, int out_size, void* d_ws, size_t ws_size,
                              hipStream_t stream) {
    const int*   row    = (const int*)d_in[0];
    const int*   col    = (const int*)d_in[1];
    const float* vals   = (const float*)d_in[2];
    const float* embeds = (const float*)d_in[3];
    float*       out    = (float*)d_out;

    const int n_edges = in_sizes[0];
    const int n_nodes = in_sizes[3] / D_FEAT;
    const int nchunks = (n_nodes + SCAN_CHUNK - 1) / SCAN_CHUNK;
    const int nb = (n_nodes + TILE_ROWS - 1) >> BUCKET_SHIFT;

    // padded bucket stride: avg + 25% + 256 (>=16 sigma for Binomial bucket sizes)
    const int avg = n_edges / (nb > 0 ? nb : 1);
    const int cap_b = avg + avg / 4 + 256;

    char* base = (char*)d_ws;

    // padded layout (no hist/scan)
    size_t offP = 0;
    uint2* tmpP           = (uint2*)(base + offP);             offP += ((size_t)nb * cap_b * 8 + 255) & ~(size_t)255;
    unsigned short* emb16P = (unsigned short*)(base + offP);   offP += ((size_t)n_nodes * D_FEAT * 2 + 255) & ~(size_t)255;
    int* bptrP            = (int*)(base + offP);               offP += (size_t)(nb + 1) * 4;
    int* bfillP           = (int*)(base + offP);               offP += (size_t)(nb + 1) * 4;
    int* qcntP            = (int*)(base + offP);               offP += 256;

    // scanned layout (exact tmp)
    size_t offS = 0;
    uint2* tmpS           = (uint2*)(base + offS);             offS += ((size_t)n_edges * 8 + 255) & ~(size_t)255;
    unsigned short* emb16S = (unsigned short*)(base + offS);   offS += ((size_t)n_nodes * D_FEAT * 2 + 255) & ~(size_t)255;
    int* bcntS            = (int*)(base + offS);               offS += (size_t)(nb + 1) * 4;
    int* bptrS            = (int*)(base + offS);               offS += (size_t)(nb + 1) * 4;
    int* bfillS           = (int*)(base + offS);               offS += (size_t)(nb + 1) * 4;
    int* qcntS            = (int*)(base + offS);               offS += 256;

    const bool common_ok = (nb <= 1023) && (n_nodes < (1 << 17));
    const bool padded_ok  = common_ok && (offP <= ws_size);
    const bool scanned_ok = common_ok && (offS <= ws_size);

    if (!padded_ok && !scanned_ok) {
        // round-2 fallback layout
        size_t off2 = 0;
        uint2* s_cv = (uint2*)(base + off2); off2 += (size_t)n_edges * 8;
        int* rc  = (int*)(base + off2); off2 += (size_t)n_nodes * 4;
        int* rf  = (int*)(base + off2); off2 += (size_t)n_nodes * 4;
        int* rp  = (int*)(base + off2); off2 += (size_t)(n_nodes + 1) * 4;
        int* cs  = (int*)(base + off2); off2 += (size_t)nchunks * 4;
        if (off2 > ws_size) {
            hipMemsetAsync(d_out, 0, (size_t)out_size * sizeof(float), stream);
            spmm_atomic_kernel<<<2048, 256, 0, stream>>>(row, col, vals, embeds, out, n_edges);
            return;
        }
        hipMemsetAsync(rc, 0, (size_t)n_nodes * 2 * sizeof(int), stream);
        hist_kernel<<<2048, 256, 0, stream>>>(row, rc, n_edges);
        scan1_kernel<<<nchunks, SCAN_BLOCK, 0, stream>>>(rc, rp, cs, n_nodes);
        scan2_kernel<<<1, 64, 0, stream>>>(cs, nchunks);
        scan3_kernel<<<(n_nodes + 256) / 256, 256, 0, stream>>>(rp, cs, n_nodes, n_edges);
        scatter_kernel<<<2048, 256, 0, stream>>>(row, col, vals, rp, rf, s_cv, n_edges);
        spmm_csr_kernel<<<4096, 256, 0, stream>>>(rp, s_cv, embeds, out, n_nodes);
        return;
    }

    uint2* tmp;
    unsigned short* embeds16;
    int *bptr, *bfill, *qcnt;

    const int part_blocks = (n_edges + PART_TILE - 1) / PART_TILE;

    if (padded_ok) {
        tmp = tmpP; embeds16 = emb16P; bptr = bptrP; bfill = bfillP; qcnt = qcntP;
        bucket_init_padded_kernel<<<(nb + 255) / 256, 256, 0, stream>>>(bptr, bfill, nb, cap_b);
    } else {
        tmp = tmpS; embeds16 = emb16S; bptr = bptrS; bfill = bfillS; qcnt = qcntS;
        hipMemsetAsync(bcntS, 0, (size_t)(nb + 1) * sizeof(int), stream);
        bucket_hist_kernel<<<512, 256, 0, stream>>>(row, bcntS, n_edges, nb);
        bucket_scan_kernel<<<1, 1024, 0, stream>>>(bcntS, bptr, bfill, nb);
    }
    hipMemsetAsync(qcnt, 0, sizeof(int), stream);

    partition_kernel<<<part_blocks, 256, 0, stream>>>(row, col, vals, bfill, tmp, n_edges, nb);

    const int n4 = n_nodes * D_FEAT / 4;
    convert_kernel<<<4096, 256, 0, stream>>>(embeds, embeds16, n4);

    // persistent blocks (2/CU x 256 CU) + dynamic queue: no scheduling tail
    spmm_bucket_q_kernel<<<512, 1024, 0, stream>>>(tmp, bptr, bfill, qcnt,
                                                   embeds16, out, n_nodes, nb);
}

// Round 13
// 225.912 us; speedup vs baseline: 1.5126x; 1.2442x over previous
//
#include <hip/hip_runtime.h>
#include <hip/hip_fp16.h>

#define D_FEAT 128

constexpr int SCAN_BLOCK = 256;
constexpr int SCAN_ITEMS = 8;
constexpr int SCAN_CHUNK = SCAN_BLOCK * SCAN_ITEMS;

constexpr int BUCKET_SHIFT = 7;      // 128 rows per bucket (round-10 proven shape)
constexpr int TILE_ROWS = 1 << BUCKET_SHIFT;
constexpr int NB_MAX = 1024;
constexpr int PART_TILE = 4096;      // 782 partition blocks @ 3.2M edges
constexpr int CAP = 6144;            // staged edges per batch (48 KB LDS)

// ---------------- fallback (round-1) atomic kernel ----------------
__global__ void __launch_bounds__(256) spmm_atomic_kernel(
    const int* __restrict__ row, const int* __restrict__ col,
    const float* __restrict__ vals, const float* __restrict__ embeds,
    float* __restrict__ out, int n_edges)
{
    const int lane = threadIdx.x & 63;
    const int wave_in_block = threadIdx.x >> 6;
    const int waves_per_block = blockDim.x >> 6;
    const int n_waves = gridDim.x * waves_per_block;
    for (int e = blockIdx.x * waves_per_block + wave_in_block; e < n_edges; e += n_waves) {
        const int r = row[e];
        const int c = col[e];
        const float v = vals[e];
        const float2 emb = *reinterpret_cast<const float2*>(&embeds[(size_t)c * D_FEAT + lane * 2]);
        float* o = &out[(size_t)r * D_FEAT + lane * 2];
        atomicAdd(o, emb.x * v);
        atomicAdd(o + 1, emb.y * v);
    }
}

// ================= fast path =================

// LDS-privatized bucket histogram (scanned mode only)
__global__ void __launch_bounds__(256) bucket_hist_kernel(
    const int* __restrict__ row, int* __restrict__ bucket_counts, int n_edges, int nb)
{
    __shared__ int cnt[NB_MAX];
    for (int b = threadIdx.x; b < nb; b += 256) cnt[b] = 0;
    __syncthreads();
    const int i = blockIdx.x * blockDim.x + threadIdx.x;
    const int stride = gridDim.x * blockDim.x;
    const int n4 = n_edges >> 2;
    for (int k = i; k < n4; k += stride) {
        int4 r4 = reinterpret_cast<const int4*>(row)[k];
        atomicAdd(&cnt[r4.x >> BUCKET_SHIFT], 1);
        atomicAdd(&cnt[r4.y >> BUCKET_SHIFT], 1);
        atomicAdd(&cnt[r4.z >> BUCKET_SHIFT], 1);
        atomicAdd(&cnt[r4.w >> BUCKET_SHIFT], 1);
    }
    for (int k = (n4 << 2) + i; k < n_edges; k += stride)
        atomicAdd(&cnt[row[k] >> BUCKET_SHIFT], 1);
    __syncthreads();
    for (int b = threadIdx.x; b < nb; b += 256) {
        int c = cnt[b];
        if (c) atomicAdd(&bucket_counts[b], c);
    }
}

// scanned mode: one block scans bucket counts -> bucket_ptr (excl) + bucket_fill
__global__ void __launch_bounds__(1024) bucket_scan_kernel(
    const int* __restrict__ bucket_counts, int* __restrict__ bucket_ptr,
    int* __restrict__ bucket_fill, int nb)
{
    __shared__ int lds[1024];
    const int t = threadIdx.x;
    lds[t] = (t < nb) ? bucket_counts[t] : 0;
    __syncthreads();
    for (int off = 1; off < 1024; off <<= 1) {
        int x = (t >= off) ? lds[t - off] : 0;
        __syncthreads();
        lds[t] += x;
        __syncthreads();
    }
    const int excl = (t == 0) ? 0 : lds[t - 1];
    if (t <= nb) bucket_ptr[t] = excl;
    if (t < nb)  bucket_fill[t] = excl;
}

// padded mode: fixed-stride bucket bases, no hist/scan needed
__global__ void __launch_bounds__(256) bucket_init_padded_kernel(
    int* __restrict__ bucket_ptr, int* __restrict__ bucket_fill, int nb, int cap_b)
{
    int b = blockIdx.x * blockDim.x + threadIdx.x;
    if (b < nb) {
        bucket_ptr[b]  = b * cap_b;
        bucket_fill[b] = b * cap_b;
    }
}

// partition edges into 128-row buckets; payload (row_local<<17 | col, half2{v,v})
__global__ void __launch_bounds__(256) partition_kernel(
    const int* __restrict__ row, const int* __restrict__ col, const float* __restrict__ vals,
    int* __restrict__ bucket_fill, uint2* __restrict__ tmp, int n_edges, int nb)
{
    __shared__ int cnt[NB_MAX];
    __shared__ int start[NB_MAX];
    const int tid = threadIdx.x;
    const int base = blockIdx.x * PART_TILE;

    for (int b = tid; b < NB_MAX; b += 256) cnt[b] = 0;
    __syncthreads();

    // count pass, int4-vectorized (PART_TILE multiple of 1024)
    #pragma unroll
    for (int k = 0; k < PART_TILE / 1024; ++k) {
        int idx = (base >> 2) + k * 256 + tid;          // int4 index
        if (idx * 4 + 3 < n_edges) {
            int4 r4 = reinterpret_cast<const int4*>(row)[idx];
            atomicAdd(&cnt[r4.x >> BUCKET_SHIFT], 1);
            atomicAdd(&cnt[r4.y >> BUCKET_SHIFT], 1);
            atomicAdd(&cnt[r4.z >> BUCKET_SHIFT], 1);
            atomicAdd(&cnt[r4.w >> BUCKET_SHIFT], 1);
        } else {
            for (int j = 0; j < 4; ++j) {
                int e = idx * 4 + j;
                if (e < n_edges) atomicAdd(&cnt[row[e] >> BUCKET_SHIFT], 1);
            }
        }
    }
    __syncthreads();

    for (int b = tid; b < nb; b += 256) {
        int c = cnt[b];
        if (c > 0) start[b] = atomicAdd(&bucket_fill[b], c);
    }
    __syncthreads();

    // scatter pass, int4/float4-vectorized
    #pragma unroll
    for (int k = 0; k < PART_TILE / 1024; ++k) {
        int idx = (base >> 2) + k * 256 + tid;
        if (idx * 4 + 3 < n_edges) {
            int4  r4 = reinterpret_cast<const int4*>(row)[idx];
            int4  c4 = reinterpret_cast<const int4*>(col)[idx];
            float4 v4 = reinterpret_cast<const float4*>(vals)[idx];
            const int rs[4]   = {r4.x, r4.y, r4.z, r4.w};
            const int cs[4]   = {c4.x, c4.y, c4.z, c4.w};
            const float vs[4] = {v4.x, v4.y, v4.z, v4.w};
            #pragma unroll
            for (int j = 0; j < 4; ++j) {
                int r = rs[j];
                int b = r >> BUCKET_SHIFT;
                int slot = atomicSub(&cnt[b], 1) - 1;
                unsigned hb = (unsigned)__half_as_ushort(__float2half(vs[j]));
                uint2 p;
                p.x = ((unsigned)(r & (TILE_ROWS - 1)) << 17) | (unsigned)cs[j];
                p.y = hb | (hb << 16);
                tmp[start[b] + slot] = p;
            }
        } else {
            for (int j = 0; j < 4; ++j) {
                int e = idx * 4 + j;
                if (e < n_edges) {
                    int r = row[e];
                    int b = r >> BUCKET_SHIFT;
                    int slot = atomicSub(&cnt[b], 1) - 1;
                    unsigned hb = (unsigned)__half_as_ushort(__float2half(vals[e]));
                    uint2 p;
                    p.x = ((unsigned)(r & (TILE_ROWS - 1)) << 17) | (unsigned)col[e];
                    p.y = hb | (hb << 16);
                    tmp[start[b] + slot] = p;
                }
            }
        }
    }
}

// ---------------- embeds f32 -> f16 ----------------
__global__ void __launch_bounds__(256) convert_kernel(
    const float* __restrict__ embeds, unsigned short* __restrict__ out16, int n4)
{
    int i = blockIdx.x * blockDim.x + threadIdx.x;
    int stride = gridDim.x * blockDim.x;
    for (; i < n4; i += stride) {
        float4 f = *reinterpret_cast<const float4*>(&embeds[(size_t)i * 4]);
        ushort4 o;
        o.x = __half_as_ushort(__float2half(f.x));
        o.y = __half_as_ushort(__float2half(f.y));
        o.z = __half_as_ushort(__float2half(f.z));
        o.w = __half_as_ushort(__float2half(f.w));
        *reinterpret_cast<ushort4*>(&out16[(size_t)i * 4]) = o;
    }
}

__device__ __forceinline__ __half2 u2h2(unsigned u)
{
    return *reinterpret_cast<__half2*>(&u);
}

// ---------------- fused sort+SpMM (round-10 structure, wave0-shfl scan) --------
// 1024 threads / 16 waves, one static block per 128-row bucket.
// Wave owns 8 rows; lanes 0-31 even edges, 32-63 odd; lane loads dwordx2
// (4 f16 feats); math is v_pk_fma_f16. Only change vs round 10: the
// 128-element exclusive scan runs in wave 0 via shfl_up (0 internal barriers)
// instead of 14-barrier block-wide Hillis-Steele.
__global__ void __launch_bounds__(1024, 8) spmm_bucket_sorted_kernel(
    const uint2* __restrict__ tmp, const int* __restrict__ bucket_ptr,
    const int* __restrict__ bucket_fill,
    const unsigned short* __restrict__ embeds16, float* __restrict__ out, int n_nodes)
{
    __shared__ uint2 sedge[CAP];          // 48 KB
    __shared__ int cnt[TILE_ROWS];
    __shared__ int rstart[TILE_ROWS];
    __shared__ int rcur[TILE_ROWS];

    const int b = blockIdx.x;
    const int lo = bucket_ptr[b];
    const int hi = bucket_fill[b];        // final fill = base + count (both modes)
    const int t = threadIdx.x;
    const int lane = t & 63;
    const int h = lane >> 5;              // half-wave id (0/1)
    const int lq = lane & 31;             // lane within half; owns feats lq*4..+3
    const int w = t >> 6;                 // wave 0..15, owns rows 8w..8w+7

    __half2 acc[16];                      // [2*rr] = feats lq*4..+1, [2*rr+1] = +2..+3
    #pragma unroll
    for (int i = 0; i < 16; ++i) acc[i] = __float2half2_rn(0.f);

    for (int cur = lo; cur < hi; cur += CAP) {
        const int bcount = min(CAP, hi - cur);

        // stage edges into registers (coalesced), CAP/1024 = 6 per thread
        uint2 e[6];
        #pragma unroll
        for (int k = 0; k < 6; ++k) {
            int idx = t + k * 1024;
            if (idx < bcount) e[k] = tmp[cur + idx];
        }
        if (t < TILE_ROWS) { cnt[t] = 0; rcur[t] = 0; }
        __syncthreads();

        // per-row count (int LDS atomics)
        #pragma unroll
        for (int k = 0; k < 6; ++k) {
            int idx = t + k * 1024;
            if (idx < bcount) atomicAdd(&cnt[(e[k].x >> 17) & (TILE_ROWS - 1)], 1);
        }
        __syncthreads();

        // wave 0: exclusive scan of cnt[128], 2 elems/lane, shfl_up (no barriers)
        if (w == 0) {
            const int c0 = cnt[2 * lane];
            const int c1 = cnt[2 * lane + 1];
            const int s = c0 + c1;
            int inc = s;
            #pragma unroll
            for (int off = 1; off < 64; off <<= 1) {
                int x = __shfl_up(inc, off);
                if (lane >= off) inc += x;
            }
            const int excl = inc - s;
            rstart[2 * lane]     = excl;
            rstart[2 * lane + 1] = excl + c0;
        }
        __syncthreads();

        // scatter row-sorted into sedge
        #pragma unroll
        for (int k = 0; k < 6; ++k) {
            int idx = t + k * 1024;
            if (idx < bcount) {
                int rl = (e[k].x >> 17) & (TILE_ROWS - 1);
                int pos = rstart[rl] + atomicAdd(&rcur[rl], 1);
                sedge[pos] = uint2{e[k].x & 0x1FFFFu, e[k].y};
            }
        }
        __syncthreads();

        // consume: wave w accumulates its 8 rows; halves take alternating edges
        #pragma unroll
        for (int rr = 0; rr < 8; ++rr) {
            const int r = w * 8 + rr;
            const int js = rstart[r];
            const int je = js + cnt[r];
            int j = js;
            for (; j + 7 < je; j += 8) {
                uint2 q0 = sedge[j + 0 + h];
                uint2 q1 = sedge[j + 2 + h];
                uint2 q2 = sedge[j + 4 + h];
                uint2 q3 = sedge[j + 6 + h];
                uint2 u0 = *reinterpret_cast<const uint2*>(&embeds16[((size_t)q0.x << 7) + lq * 4]);
                uint2 u1 = *reinterpret_cast<const uint2*>(&embeds16[((size_t)q1.x << 7) + lq * 4]);
                uint2 u2 = *reinterpret_cast<const uint2*>(&embeds16[((size_t)q2.x << 7) + lq * 4]);
                uint2 u3 = *reinterpret_cast<const uint2*>(&embeds16[((size_t)q3.x << 7) + lq * 4]);
                acc[2*rr]   = __hfma2(u2h2(q0.y), u2h2(u0.x), acc[2*rr]);
                acc[2*rr+1] = __hfma2(u2h2(q0.y), u2h2(u0.y), acc[2*rr+1]);
                acc[2*rr]   = __hfma2(u2h2(q1.y), u2h2(u1.x), acc[2*rr]);
                acc[2*rr+1] = __hfma2(u2h2(q1.y), u2h2(u1.y), acc[2*rr+1]);
                acc[2*rr]   = __hfma2(u2h2(q2.y), u2h2(u2.x), acc[2*rr]);
                acc[2*rr+1] = __hfma2(u2h2(q2.y), u2h2(u2.y), acc[2*rr+1]);
                acc[2*rr]   = __hfma2(u2h2(q3.y), u2h2(u3.x), acc[2*rr]);
                acc[2*rr+1] = __hfma2(u2h2(q3.y), u2h2(u3.y), acc[2*rr+1]);
            }
            for (; j + 1 < je; j += 2) {
                uint2 q = sedge[j + h];
                uint2 u = *reinterpret_cast<const uint2*>(&embeds16[((size_t)q.x << 7) + lq * 4]);
                acc[2*rr]   = __hfma2(u2h2(q.y), u2h2(u.x), acc[2*rr]);
                acc[2*rr+1] = __hfma2(u2h2(q.y), u2h2(u.y), acc[2*rr+1]);
            }
            if (j < je && h == 0) {      // single leftover edge: half 0 only
                uint2 q = sedge[j];
                uint2 u = *reinterpret_cast<const uint2*>(&embeds16[((size_t)q.x << 7) + lq * 4]);
                acc[2*rr]   = __hfma2(u2h2(q.y), u2h2(u.x), acc[2*rr]);
                acc[2*rr+1] = __hfma2(u2h2(q.y), u2h2(u.y), acc[2*rr+1]);
            }
        }
        __syncthreads();   // protect sedge before next batch
    }

    // convert to f32, merge halves (disjoint edge subsets), write
    float4 facc[8];
    #pragma unroll
    for (int rr = 0; rr < 8; ++rr) {
        float2 a = __half22float2(acc[2*rr]);
        float2 bq = __half22float2(acc[2*rr+1]);
        facc[rr] = float4{a.x, a.y, bq.x, bq.y};
        facc[rr].x += __shfl_xor(facc[rr].x, 32);
        facc[rr].y += __shfl_xor(facc[rr].y, 32);
        facc[rr].z += __shfl_xor(facc[rr].z, 32);
        facc[rr].w += __shfl_xor(facc[rr].w, 32);
    }

    // half h writes rows w*8 + k + 4h (static indices + cndmask select)
    const int rbase = b << BUCKET_SHIFT;
    #pragma unroll
    for (int k = 0; k < 4; ++k) {
        float4 a0 = facc[k];
        float4 a1 = facc[k + 4];
        float4 vv;
        vv.x = h ? a1.x : a0.x;
        vv.y = h ? a1.y : a0.y;
        vv.z = h ? a1.z : a0.z;
        vv.w = h ? a1.w : a0.w;
        int r = rbase + w * 8 + k + 4 * h;
        if (r < n_nodes)
            *reinterpret_cast<float4*>(&out[(size_t)r * D_FEAT + lq * 4]) = vv;
    }
}

// ================= round-2 fallback pieces =================
__global__ void hist_kernel(const int* __restrict__ row, int* __restrict__ counts, int n)
{
    int i = blockIdx.x * blockDim.x + threadIdx.x;
    int stride = gridDim.x * blockDim.x;
    for (; i < n; i += stride) atomicAdd(&counts[row[i]], 1);
}

__global__ void __launch_bounds__(SCAN_BLOCK) scan1_kernel(
    const int* __restrict__ counts, int* __restrict__ scan_out,
    int* __restrict__ chunk_sums, int n)
{
    __shared__ int lds[SCAN_BLOCK];
    const int chunk = blockIdx.x;
    const int base = chunk * SCAN_CHUNK;
    const int tbase = base + threadIdx.x * SCAN_ITEMS;

    int pref[SCAN_ITEMS];
    int tsum = 0;
    for (int k = 0; k < SCAN_ITEMS; ++k) {
        int idx = tbase + k;
        int v = (idx < n) ? counts[idx] : 0;
        pref[k] = tsum;
        tsum += v;
    }
    lds[threadIdx.x] = tsum;
    __syncthreads();
    for (int off = 1; off < SCAN_BLOCK; off <<= 1) {
        int v = (threadIdx.x >= off) ? lds[threadIdx.x - off] : 0;
        __syncthreads();
        lds[threadIdx.x] += v;
        __syncthreads();
    }
    const int texcl = (threadIdx.x == 0) ? 0 : lds[threadIdx.x - 1];
    for (int k = 0; k < SCAN_ITEMS; ++k) {
        int idx = tbase + k;
        if (idx < n) scan_out[idx] = texcl + pref[k];
    }
    if (threadIdx.x == SCAN_BLOCK - 1) chunk_sums[chunk] = lds[SCAN_BLOCK - 1];
}

__global__ void scan2_kernel(int* chunk_sums, int nchunks)
{
    if (blockIdx.x == 0 && threadIdx.x == 0) {
        int acc = 0;
        for (int i = 0; i < nchunks; ++i) { int v = chunk_sums[i]; chunk_sums[i] = acc; acc += v; }
    }
}

__global__ void scan3_kernel(int* __restrict__ row_ptr, const int* __restrict__ chunk_sums,
                             int n, int n_edges)
{
    int i = blockIdx.x * blockDim.x + threadIdx.x;
    if (i < n) row_ptr[i] += chunk_sums[i / SCAN_CHUNK];
    if (i == 0) row_ptr[n] = n_edges;
}

__global__ void scatter_kernel(const int* __restrict__ row, const int* __restrict__ col,
                               const float* __restrict__ vals,
                               const int* __restrict__ row_ptr, int* __restrict__ row_fill,
                               uint2* __restrict__ sorted_cv, int n_edges)
{
    int i = blockIdx.x * blockDim.x + threadIdx.x;
    int stride = gridDim.x * blockDim.x;
    for (; i < n_edges; i += stride) {
        int r = row[i];
        int pos = row_ptr[r] + atomicAdd(&row_fill[r], 1);
        uint2 cv;
        cv.x = (unsigned)col[i];
        cv.y = __float_as_uint(vals[i]);
        sorted_cv[pos] = cv;
    }
}

__global__ void __launch_bounds__(256) spmm_csr_kernel(
    const int* __restrict__ row_ptr, const uint2* __restrict__ sorted_cv,
    const float* __restrict__ embeds, float* __restrict__ out, int n_rows)
{
    const int lane = threadIdx.x & 63;
    const int wid = (blockIdx.x * blockDim.x + threadIdx.x) >> 6;
    const int n_waves = (gridDim.x * blockDim.x) >> 6;

    for (int r = wid; r < n_rows; r += n_waves) {
        const int start = row_ptr[r];
        const int end   = row_ptr[r + 1];
        float2 acc = {0.f, 0.f};
        for (int j = start; j < end; ++j) {
            uint2 cv = sorted_cv[j];
            const float2 e = *reinterpret_cast<const float2*>(&embeds[(size_t)cv.x * D_FEAT + lane * 2]);
            const float v = __uint_as_float(cv.y);
            acc.x += v * e.x;
            acc.y += v * e.y;
        }
        *reinterpret_cast<float2*>(&out[(size_t)r * D_FEAT + lane * 2]) = acc;
    }
}

extern "C" void kernel_launch(void* const* d_in, const int* in_sizes, int n_in,
                              void* d_out, int out_size, void* d_ws, size_t ws_size,
                              hipStream_t stream) {
    const int*   row    = (const int*)d_in[0];
    const int*   col    = (const int*)d_in[1];
    const float* vals   = (const float*)d_in[2];
    const float* embeds = (const float*)d_in[3];
    float*       out    = (float*)d_out;

    const int n_edges = in_sizes[0];
    const int n_nodes = in_sizes[3] / D_FEAT;
    const int nchunks = (n_nodes + SCAN_CHUNK - 1) / SCAN_CHUNK;
    const int nb = (n_nodes + TILE_ROWS - 1) >> BUCKET_SHIFT;

    // padded bucket stride: avg + 25% + 256 (>=16 sigma for Binomial bucket sizes)
    const int avg = n_edges / (nb > 0 ? nb : 1);
    const int cap_b = avg + avg / 4 + 256;

    char* base = (char*)d_ws;

    // padded layout (no hist/scan)
    size_t offP = 0;
    uint2* tmpP           = (uint2*)(base + offP);             offP += ((size_t)nb * cap_b * 8 + 255) & ~(size_t)255;
    unsigned short* emb16P = (unsigned short*)(base + offP);   offP += ((size_t)n_nodes * D_FEAT * 2 + 255) & ~(size_t)255;
    int* bptrP            = (int*)(base + offP);               offP += (size_t)(nb + 1) * 4;
    int* bfillP           = (int*)(base + offP);               offP += (size_t)(nb + 1) * 4;

    // scanned layout (exact tmp)
    size_t offS = 0;
    uint2* tmpS           = (uint2*)(base + offS);             offS += ((size_t)n_edges * 8 + 255) & ~(size_t)255;
    unsigned short* emb16S = (unsigned short*)(base + offS);   offS += ((size_t)n_nodes * D_FEAT * 2 + 255) & ~(size_t)255;
    int* bcntS            = (int*)(base + offS);               offS += (size_t)(nb + 1) * 4;
    int* bptrS            = (int*)(base + offS);               offS += (size_t)(nb + 1) * 4;
    int* bfillS           = (int*)(base + offS);               offS += (size_t)(nb + 1) * 4;

    const bool common_ok = (nb <= 1023) && (n_nodes < (1 << 17));
    const bool padded_ok  = common_ok && (offP <= ws_size);
    const bool scanned_ok = common_ok && (offS <= ws_size);

    if (!padded_ok && !scanned_ok) {
        // round-2 fallback layout
        size_t off2 = 0;
        uint2* s_cv = (uint2*)(base + off2); off2 += (size_t)n_edges * 8;
        int* rc  = (int*)(base + off2); off2 += (size_t)n_nodes * 4;
        int* rf  = (int*)(base + off2); off2 += (size_t)n_nodes * 4;
        int* rp  = (int*)(base + off2); off2 += (size_t)(n_nodes + 1) * 4;
        int* cs  = (int*)(base + off2); off2 += (size_t)nchunks * 4;
        if (off2 > ws_size) {
            hipMemsetAsync(d_out, 0, (size_t)out_size * sizeof(float), stream);
            spmm_atomic_kernel<<<2048, 256, 0, stream>>>(row, col, vals, embeds, out, n_edges);
            return;
        }
        hipMemsetAsync(rc, 0, (size_t)n_nodes * 2 * sizeof(int), stream);
        hist_kernel<<<2048, 256, 0, stream>>>(row, rc, n_edges);
        scan1_kernel<<<nchunks, SCAN_BLOCK, 0, stream>>>(rc, rp, cs, n_nodes);
        scan2_kernel<<<1, 64, 0, stream>>>(cs, nchunks);
        scan3_kernel<<<(n_nodes + 256) / 256, 256, 0, stream>>>(rp, cs, n_nodes, n_edges);
        scatter_kernel<<<2048, 256, 0, stream>>>(row, col, vals, rp, rf, s_cv, n_edges);
        spmm_csr_kernel<<<4096, 256, 0, stream>>>(rp, s_cv, embeds, out, n_nodes);
        return;
    }

    uint2* tmp;
    unsigned short* embeds16;
    int *bptr, *bfill;

    const int part_blocks = (n_edges + PART_TILE - 1) / PART_TILE;

    if (padded_ok) {
        tmp = tmpP; embeds16 = emb16P; bptr = bptrP; bfill = bfillP;
        bucket_init_padded_kernel<<<(nb + 255) / 256, 256, 0, stream>>>(bptr, bfill, nb, cap_b);
    } else {
        tmp = tmpS; embeds16 = emb16S; bptr = bptrS; bfill = bfillS;
        hipMemsetAsync(bcntS, 0, (size_t)(nb + 1) * sizeof(int), stream);
        bucket_hist_kernel<<<512, 256, 0, stream>>>(row, bcntS, n_edges, nb);
        bucket_scan_kernel<<<1, 1024, 0, stream>>>(bcntS, bptr, bfill, nb);
    }

    partition_kernel<<<part_blocks, 256, 0, stream>>>(row, col, vals, bfill, tmp, n_edges, nb);

    const int n4 = n_nodes * D_FEAT / 4;
    convert_kernel<<<4096, 256, 0, stream>>>(embeds, embeds16, n4);

    // static grid: one block per bucket (round-10 proven launch shape)
    spmm_bucket_sorted_kernel<<<nb, 1024, 0, stream>>>(tmp, bptr, bfill, embeds16, out, n_nodes);
}

// Round 14
// 208.517 us; speedup vs baseline: 1.6388x; 1.0834x over previous
//
#include <hip/hip_runtime.h>
#include <hip/hip_fp16.h>

#define D_FEAT 128

constexpr int SCAN_BLOCK = 256;
constexpr int SCAN_ITEMS = 8;
constexpr int SCAN_CHUNK = SCAN_BLOCK * SCAN_ITEMS;

constexpr int BUCKET_SHIFT = 7;      // 128 rows per bucket
constexpr int TILE_ROWS = 1 << BUCKET_SHIFT;
constexpr int NB_MAX = 1024;
constexpr int PART_TILE = 4096;      // 782 partition blocks @ 3.2M edges
constexpr int CAP = 6144;            // staged edges per batch (48 KB LDS)
constexpr int NKEY = 256;            // 2 col-slices x 128 rows

// ---------------- fallback (round-1) atomic kernel ----------------
__global__ void __launch_bounds__(256) spmm_atomic_kernel(
    const int* __restrict__ row, const int* __restrict__ col,
    const float* __restrict__ vals, const float* __restrict__ embeds,
    float* __restrict__ out, int n_edges)
{
    const int lane = threadIdx.x & 63;
    const int wave_in_block = threadIdx.x >> 6;
    const int waves_per_block = blockDim.x >> 6;
    const int n_waves = gridDim.x * waves_per_block;
    for (int e = blockIdx.x * waves_per_block + wave_in_block; e < n_edges; e += n_waves) {
        const int r = row[e];
        const int c = col[e];
        const float v = vals[e];
        const float2 emb = *reinterpret_cast<const float2*>(&embeds[(size_t)c * D_FEAT + lane * 2]);
        float* o = &out[(size_t)r * D_FEAT + lane * 2];
        atomicAdd(o, emb.x * v);
        atomicAdd(o + 1, emb.y * v);
    }
}

// ================= fast path =================

// LDS-privatized bucket histogram (scanned mode only)
__global__ void __launch_bounds__(256) bucket_hist_kernel(
    const int* __restrict__ row, int* __restrict__ bucket_counts, int n_edges, int nb)
{
    __shared__ int cnt[NB_MAX];
    for (int b = threadIdx.x; b < nb; b += 256) cnt[b] = 0;
    __syncthreads();
    const int i = blockIdx.x * blockDim.x + threadIdx.x;
    const int stride = gridDim.x * blockDim.x;
    const int n4 = n_edges >> 2;
    for (int k = i; k < n4; k += stride) {
        int4 r4 = reinterpret_cast<const int4*>(row)[k];
        atomicAdd(&cnt[r4.x >> BUCKET_SHIFT], 1);
        atomicAdd(&cnt[r4.y >> BUCKET_SHIFT], 1);
        atomicAdd(&cnt[r4.z >> BUCKET_SHIFT], 1);
        atomicAdd(&cnt[r4.w >> BUCKET_SHIFT], 1);
    }
    for (int k = (n4 << 2) + i; k < n_edges; k += stride)
        atomicAdd(&cnt[row[k] >> BUCKET_SHIFT], 1);
    __syncthreads();
    for (int b = threadIdx.x; b < nb; b += 256) {
        int c = cnt[b];
        if (c) atomicAdd(&bucket_counts[b], c);
    }
}

// scanned mode: one block scans bucket counts -> bucket_ptr (excl) + bucket_fill
__global__ void __launch_bounds__(1024) bucket_scan_kernel(
    const int* __restrict__ bucket_counts, int* __restrict__ bucket_ptr,
    int* __restrict__ bucket_fill, int nb)
{
    __shared__ int lds[1024];
    const int t = threadIdx.x;
    lds[t] = (t < nb) ? bucket_counts[t] : 0;
    __syncthreads();
    for (int off = 1; off < 1024; off <<= 1) {
        int x = (t >= off) ? lds[t - off] : 0;
        __syncthreads();
        lds[t] += x;
        __syncthreads();
    }
    const int excl = (t == 0) ? 0 : lds[t - 1];
    if (t <= nb) bucket_ptr[t] = excl;
    if (t < nb)  bucket_fill[t] = excl;
}

// padded mode: fixed-stride bucket bases, no hist/scan needed
__global__ void __launch_bounds__(256) bucket_init_padded_kernel(
    int* __restrict__ bucket_ptr, int* __restrict__ bucket_fill, int nb, int cap_b)
{
    int b = blockIdx.x * blockDim.x + threadIdx.x;
    if (b < nb) {
        bucket_ptr[b]  = b * cap_b;
        bucket_fill[b] = b * cap_b;
    }
}

// partition edges into 128-row buckets; payload (row_local<<17 | col, half2{v,v})
__global__ void __launch_bounds__(256) partition_kernel(
    const int* __restrict__ row, const int* __restrict__ col, const float* __restrict__ vals,
    int* __restrict__ bucket_fill, uint2* __restrict__ tmp, int n_edges, int nb)
{
    __shared__ int cnt[NB_MAX];
    __shared__ int start[NB_MAX];
    const int tid = threadIdx.x;
    const int base = blockIdx.x * PART_TILE;

    for (int b = tid; b < NB_MAX; b += 256) cnt[b] = 0;
    __syncthreads();

    // count pass, int4-vectorized (PART_TILE multiple of 1024)
    #pragma unroll
    for (int k = 0; k < PART_TILE / 1024; ++k) {
        int idx = (base >> 2) + k * 256 + tid;          // int4 index
        if (idx * 4 + 3 < n_edges) {
            int4 r4 = reinterpret_cast<const int4*>(row)[idx];
            atomicAdd(&cnt[r4.x >> BUCKET_SHIFT], 1);
            atomicAdd(&cnt[r4.y >> BUCKET_SHIFT], 1);
            atomicAdd(&cnt[r4.z >> BUCKET_SHIFT], 1);
            atomicAdd(&cnt[r4.w >> BUCKET_SHIFT], 1);
        } else {
            for (int j = 0; j < 4; ++j) {
                int e = idx * 4 + j;
                if (e < n_edges) atomicAdd(&cnt[row[e] >> BUCKET_SHIFT], 1);
            }
        }
    }
    __syncthreads();

    for (int b = tid; b < nb; b += 256) {
        int c = cnt[b];
        if (c > 0) start[b] = atomicAdd(&bucket_fill[b], c);
    }
    __syncthreads();

    // scatter pass, int4/float4-vectorized
    #pragma unroll
    for (int k = 0; k < PART_TILE / 1024; ++k) {
        int idx = (base >> 2) + k * 256 + tid;
        if (idx * 4 + 3 < n_edges) {
            int4  r4 = reinterpret_cast<const int4*>(row)[idx];
            int4  c4 = reinterpret_cast<const int4*>(col)[idx];
            float4 v4 = reinterpret_cast<const float4*>(vals)[idx];
            const int rs[4]   = {r4.x, r4.y, r4.z, r4.w};
            const int cs[4]   = {c4.x, c4.y, c4.z, c4.w};
            const float vs[4] = {v4.x, v4.y, v4.z, v4.w};
            #pragma unroll
            for (int j = 0; j < 4; ++j) {
                int r = rs[j];
                int b = r >> BUCKET_SHIFT;
                int slot = atomicSub(&cnt[b], 1) - 1;
                unsigned hb = (unsigned)__half_as_ushort(__float2half(vs[j]));
                uint2 p;
                p.x = ((unsigned)(r & (TILE_ROWS - 1)) << 17) | (unsigned)cs[j];
                p.y = hb | (hb << 16);
                tmp[start[b] + slot] = p;
            }
        } else {
            for (int j = 0; j < 4; ++j) {
                int e = idx * 4 + j;
                if (e < n_edges) {
                    int r = row[e];
                    int b = r >> BUCKET_SHIFT;
                    int slot = atomicSub(&cnt[b], 1) - 1;
                    unsigned hb = (unsigned)__half_as_ushort(__float2half(vals[e]));
                    uint2 p;
                    p.x = ((unsigned)(r & (TILE_ROWS - 1)) << 17) | (unsigned)col[e];
                    p.y = hb | (hb << 16);
                    tmp[start[b] + slot] = p;
                }
            }
        }
    }
}

// ---------------- embeds f32 -> f16 ----------------
__global__ void __launch_bounds__(256) convert_kernel(
    const float* __restrict__ embeds, unsigned short* __restrict__ out16, int n4)
{
    int i = blockIdx.x * blockDim.x + threadIdx.x;
    int stride = gridDim.x * blockDim.x;
    for (; i < n4; i += stride) {
        float4 f = *reinterpret_cast<const float4*>(&embeds[(size_t)i * 4]);
        ushort4 o;
        o.x = __half_as_ushort(__float2half(f.x));
        o.y = __half_as_ushort(__float2half(f.y));
        o.z = __half_as_ushort(__float2half(f.z));
        o.w = __half_as_ushort(__float2half(f.w));
        *reinterpret_cast<ushort4*>(&out16[(size_t)i * 4]) = o;
    }
}

__device__ __forceinline__ __half2 u2h2(unsigned u)
{
    return *reinterpret_cast<__half2*>(&u);
}

// ---------------- fused sort+SpMM: 2-slice sort key (round-13 + slicing) ------
// Sort key = (col>>16)<<7 | row_local -> 256 keys. Consume is slice-major, so
// all resident blocks sweep embeds16 halves (16MB then 8.4MB) in phase,
// halving the instantaneous gather working set per XCD L2. Segments average
// ~16-21 edges, keeping the unrolled consume loop efficient (r7 failure mode
// was 3.4-edge segments at 7 slices).
__global__ void __launch_bounds__(1024, 8) spmm_bucket_sorted_kernel(
    const uint2* __restrict__ tmp, const int* __restrict__ bucket_ptr,
    const int* __restrict__ bucket_fill,
    const unsigned short* __restrict__ embeds16, float* __restrict__ out, int n_nodes)
{
    __shared__ uint2 sedge[CAP];          // 48 KB
    __shared__ int cnt[NKEY];
    __shared__ int rstart[NKEY];
    __shared__ int rcur[NKEY];

    const int b = blockIdx.x;
    const int lo = bucket_ptr[b];
    const int hi = bucket_fill[b];        // final fill = base + count (both modes)
    const int t = threadIdx.x;
    const int lane = t & 63;
    const int h = lane >> 5;              // half-wave id (0/1)
    const int lq = lane & 31;             // lane within half; owns feats lq*4..+3
    const int w = t >> 6;                 // wave 0..15, owns rows 8w..8w+7

    __half2 acc[16];                      // [2*rr] = feats lq*4..+1, [2*rr+1] = +2..+3
    #pragma unroll
    for (int i = 0; i < 16; ++i) acc[i] = __float2half2_rn(0.f);

    for (int cur = lo; cur < hi; cur += CAP) {
        const int bcount = min(CAP, hi - cur);

        // stage edges into registers (coalesced), CAP/1024 = 6 per thread
        uint2 e[6];
        #pragma unroll
        for (int k = 0; k < 6; ++k) {
            int idx = t + k * 1024;
            if (idx < bcount) e[k] = tmp[cur + idx];
        }
        if (t < NKEY) { cnt[t] = 0; rcur[t] = 0; }
        __syncthreads();

        // per-key count: key = slice(col bit16)<<7 | row_local
        #pragma unroll
        for (int k = 0; k < 6; ++k) {
            int idx = t + k * 1024;
            if (idx < bcount) {
                unsigned px = e[k].x;
                int key = (int)(((px >> 16) & 1u) << 7) | (int)((px >> 17) & (TILE_ROWS - 1));
                atomicAdd(&cnt[key], 1);
            }
        }
        __syncthreads();

        // wave 0: exclusive scan of cnt[256], 4 elems/lane, shfl_up (no barriers)
        if (w == 0) {
            const int c0 = cnt[4 * lane];
            const int c1 = cnt[4 * lane + 1];
            const int c2 = cnt[4 * lane + 2];
            const int c3 = cnt[4 * lane + 3];
            const int s = c0 + c1 + c2 + c3;
            int inc = s;
            #pragma unroll
            for (int off = 1; off < 64; off <<= 1) {
                int x = __shfl_up(inc, off);
                if (lane >= off) inc += x;
            }
            const int excl = inc - s;
            rstart[4 * lane]     = excl;
            rstart[4 * lane + 1] = excl + c0;
            rstart[4 * lane + 2] = excl + c0 + c1;
            rstart[4 * lane + 3] = excl + c0 + c1 + c2;
        }
        __syncthreads();

        // scatter key-sorted into sedge
        #pragma unroll
        for (int k = 0; k < 6; ++k) {
            int idx = t + k * 1024;
            if (idx < bcount) {
                unsigned px = e[k].x;
                int key = (int)(((px >> 16) & 1u) << 7) | (int)((px >> 17) & (TILE_ROWS - 1));
                int pos = rstart[key] + atomicAdd(&rcur[key], 1);
                sedge[pos] = uint2{px & 0x1FFFFu, e[k].y};
            }
        }
        __syncthreads();

        // consume slice-major: wave w rows 8w..8w+7, slice s = 0 then 1
        for (int s = 0; s < 2; ++s) {
            #pragma unroll
            for (int rr = 0; rr < 8; ++rr) {
                const int key = (s << 7) | (w * 8 + rr);
                const int js = rstart[key];
                const int je = js + cnt[key];
                int j = js;
                for (; j + 7 < je; j += 8) {
                    uint2 q0 = sedge[j + 0 + h];
                    uint2 q1 = sedge[j + 2 + h];
                    uint2 q2 = sedge[j + 4 + h];
                    uint2 q3 = sedge[j + 6 + h];
                    uint2 u0 = *reinterpret_cast<const uint2*>(&embeds16[((size_t)q0.x << 7) + lq * 4]);
                    uint2 u1 = *reinterpret_cast<const uint2*>(&embeds16[((size_t)q1.x << 7) + lq * 4]);
                    uint2 u2 = *reinterpret_cast<const uint2*>(&embeds16[((size_t)q2.x << 7) + lq * 4]);
                    uint2 u3 = *reinterpret_cast<const uint2*>(&embeds16[((size_t)q3.x << 7) + lq * 4]);
                    acc[2*rr]   = __hfma2(u2h2(q0.y), u2h2(u0.x), acc[2*rr]);
                    acc[2*rr+1] = __hfma2(u2h2(q0.y), u2h2(u0.y), acc[2*rr+1]);
                    acc[2*rr]   = __hfma2(u2h2(q1.y), u2h2(u1.x), acc[2*rr]);
                    acc[2*rr+1] = __hfma2(u2h2(q1.y), u2h2(u1.y), acc[2*rr+1]);
                    acc[2*rr]   = __hfma2(u2h2(q2.y), u2h2(u2.x), acc[2*rr]);
                    acc[2*rr+1] = __hfma2(u2h2(q2.y), u2h2(u2.y), acc[2*rr+1]);
                    acc[2*rr]   = __hfma2(u2h2(q3.y), u2h2(u3.x), acc[2*rr]);
                    acc[2*rr+1] = __hfma2(u2h2(q3.y), u2h2(u3.y), acc[2*rr+1]);
                }
                for (; j + 1 < je; j += 2) {
                    uint2 q = sedge[j + h];
                    uint2 u = *reinterpret_cast<const uint2*>(&embeds16[((size_t)q.x << 7) + lq * 4]);
                    acc[2*rr]   = __hfma2(u2h2(q.y), u2h2(u.x), acc[2*rr]);
                    acc[2*rr+1] = __hfma2(u2h2(q.y), u2h2(u.y), acc[2*rr+1]);
                }
                if (j < je && h == 0) {      // single leftover edge: half 0 only
                    uint2 q = sedge[j];
                    uint2 u = *reinterpret_cast<const uint2*>(&embeds16[((size_t)q.x << 7) + lq * 4]);
                    acc[2*rr]   = __hfma2(u2h2(q.y), u2h2(u.x), acc[2*rr]);
                    acc[2*rr+1] = __hfma2(u2h2(q.y), u2h2(u.y), acc[2*rr+1]);
                }
            }
        }
        __syncthreads();   // protect sedge before next batch
    }

    // convert to f32, merge halves (disjoint edge subsets), write
    float4 facc[8];
    #pragma unroll
    for (int rr = 0; rr < 8; ++rr) {
        float2 a = __half22float2(acc[2*rr]);
        float2 bq = __half22float2(acc[2*rr+1]);
        facc[rr] = float4{a.x, a.y, bq.x, bq.y};
        facc[rr].x += __shfl_xor(facc[rr].x, 32);
        facc[rr].y += __shfl_xor(facc[rr].y, 32);
        facc[rr].z += __shfl_xor(facc[rr].z, 32);
        facc[rr].w += __shfl_xor(facc[rr].w, 32);
    }

    // half h writes rows w*8 + k + 4h (static indices + cndmask select)
    const int rbase = b << BUCKET_SHIFT;
    #pragma unroll
    for (int k = 0; k < 4; ++k) {
        float4 a0 = facc[k];
        float4 a1 = facc[k + 4];
        float4 vv;
        vv.x = h ? a1.x : a0.x;
        vv.y = h ? a1.y : a0.y;
        vv.z = h ? a1.z : a0.z;
        vv.w = h ? a1.w : a0.w;
        int r = rbase + w * 8 + k + 4 * h;
        if (r < n_nodes)
            *reinterpret_cast<float4*>(&out[(size_t)r * D_FEAT + lq * 4]) = vv;
    }
}

// ================= round-2 fallback pieces =================
__global__ void hist_kernel(const int* __restrict__ row, int* __restrict__ counts, int n)
{
    int i = blockIdx.x * blockDim.x + threadIdx.x;
    int stride = gridDim.x * blockDim.x;
    for (; i < n; i += stride) atomicAdd(&counts[row[i]], 1);
}

__global__ void __launch_bounds__(SCAN_BLOCK) scan1_kernel(
    const int* __restrict__ counts, int* __restrict__ scan_out,
    int* __restrict__ chunk_sums, int n)
{
    __shared__ int lds[SCAN_BLOCK];
    const int chunk = blockIdx.x;
    const int base = chunk * SCAN_CHUNK;
    const int tbase = base + threadIdx.x * SCAN_ITEMS;

    int pref[SCAN_ITEMS];
    int tsum = 0;
    for (int k = 0; k < SCAN_ITEMS; ++k) {
        int idx = tbase + k;
        int v = (idx < n) ? counts[idx] : 0;
        pref[k] = tsum;
        tsum += v;
    }
    lds[threadIdx.x] = tsum;
    __syncthreads();
    for (int off = 1; off < SCAN_BLOCK; off <<= 1) {
        int v = (threadIdx.x >= off) ? lds[threadIdx.x - off] : 0;
        __syncthreads();
        lds[threadIdx.x] += v;
        __syncthreads();
    }
    const int texcl = (threadIdx.x == 0) ? 0 : lds[threadIdx.x - 1];
    for (int k = 0; k < SCAN_ITEMS; ++k) {
        int idx = tbase + k;
        if (idx < n) scan_out[idx] = texcl + pref[k];
    }
    if (threadIdx.x == SCAN_BLOCK - 1) chunk_sums[chunk] = lds[SCAN_BLOCK - 1];
}

__global__ void scan2_kernel(int* chunk_sums, int nchunks)
{
    if (blockIdx.x == 0 && threadIdx.x == 0) {
        int acc = 0;
        for (int i = 0; i < nchunks; ++i) { int v = chunk_sums[i]; chunk_sums[i] = acc; acc += v; }
    }
}

__global__ void scan3_kernel(int* __restrict__ row_ptr, const int* __restrict__ chunk_sums,
                             int n, int n_edges)
{
    int i = blockIdx.x * blockDim.x + threadIdx.x;
    if (i < n) row_ptr[i] += chunk_sums[i / SCAN_CHUNK];
    if (i == 0) row_ptr[n] = n_edges;
}

__global__ void scatter_kernel(const int* __restrict__ row, const int* __restrict__ col,
                               const float* __restrict__ vals,
                               const int* __restrict__ row_ptr, int* __restrict__ row_fill,
                               uint2* __restrict__ sorted_cv, int n_edges)
{
    int i = blockIdx.x * blockDim.x + threadIdx.x;
    int stride = gridDim.x * blockDim.x;
    for (; i < n_edges; i += stride) {
        int r = row[i];
        int pos = row_ptr[r] + atomicAdd(&row_fill[r], 1);
        uint2 cv;
        cv.x = (unsigned)col[i];
        cv.y = __float_as_uint(vals[i]);
        sorted_cv[pos] = cv;
    }
}

__global__ void __launch_bounds__(256) spmm_csr_kernel(
    const int* __restrict__ row_ptr, const uint2* __restrict__ sorted_cv,
    const float* __restrict__ embeds, float* __restrict__ out, int n_rows)
{
    const int lane = threadIdx.x & 63;
    const int wid = (blockIdx.x * blockDim.x + threadIdx.x) >> 6;
    const int n_waves = (gridDim.x * blockDim.x) >> 6;

    for (int r = wid; r < n_rows; r += n_waves) {
        const int start = row_ptr[r];
        const int end   = row_ptr[r + 1];
        float2 acc = {0.f, 0.f};
        for (int j = start; j < end; ++j) {
            uint2 cv = sorted_cv[j];
            const float2 e = *reinterpret_cast<const float2*>(&embeds[(size_t)cv.x * D_FEAT + lane * 2]);
            const float v = __uint_as_float(cv.y);
            acc.x += v * e.x;
            acc.y += v * e.y;
        }
        *reinterpret_cast<float2*>(&out[(size_t)r * D_FEAT + lane * 2]) = acc;
    }
}

extern "C" void kernel_launch(void* const* d_in, const int* in_sizes, int n_in,
                              void* d_out, int out_size, void* d_ws, size_t ws_size,
                              hipStream_t stream) {
    const int*   row    = (const int*)d_in[0];
    const int*   col    = (const int*)d_in[1];
    const float* vals   = (const float*)d_in[2];
    const float* embeds = (const float*)d_in[3];
    float*       out    = (float*)d_out;

    const int n_edges = in_sizes[0];
    const int n_nodes = in_sizes[3] / D_FEAT;
    const int nchunks = (n_nodes + SCAN_CHUNK - 1) / SCAN_CHUNK;
    const int nb = (n_nodes + TILE_ROWS - 1) >> BUCKET_SHIFT;

    // padded bucket stride: avg + 25% + 256 (>=16 sigma for Binomial bucket sizes)
    const int avg = n_edges / (nb > 0 ? nb : 1);
    const int cap_b = avg + avg / 4 + 256;

    char* base = (char*)d_ws;

    // padded layout (no hist/scan)
    size_t offP = 0;
    uint2* tmpP           = (uint2*)(base + offP);             offP += ((size_t)nb * cap_b * 8 + 255) & ~(size_t)255;
    unsigned short* emb16P = (unsigned short*)(base + offP);   offP += ((size_t)n_nodes * D_FEAT * 2 + 255) & ~(size_t)255;
    int* bptrP            = (int*)(base + offP);               offP += (size_t)(nb + 1) * 4;
    int* bfillP           = (int*)(base + offP);               offP += (size_t)(nb + 1) * 4;

    // scanned layout (exact tmp)
    size_t offS = 0;
    uint2* tmpS           = (uint2*)(base + offS);             offS += ((size_t)n_edges * 8 + 255) & ~(size_t)255;
    unsigned short* emb16S = (unsigned short*)(base + offS);   offS += ((size_t)n_nodes * D_FEAT * 2 + 255) & ~(size_t)255;
    int* bcntS            = (int*)(base + offS);               offS += (size_t)(nb + 1) * 4;
    int* bptrS            = (int*)(base + offS);               offS += (size_t)(nb + 1) * 4;
    int* bfillS           = (int*)(base + offS);               offS += (size_t)(nb + 1) * 4;

    const bool common_ok = (nb <= 1023) && (n_nodes < (1 << 17));
    const bool padded_ok  = common_ok && (offP <= ws_size);
    const bool scanned_ok = common_ok && (offS <= ws_size);

    if (!padded_ok && !scanned_ok) {
        // round-2 fallback layout
        size_t off2 = 0;
        uint2* s_cv = (uint2*)(base + off2); off2 += (size_t)n_edges * 8;
        int* rc  = (int*)(base + off2); off2 += (size_t)n_nodes * 4;
        int* rf  = (int*)(base + off2); off2 += (size_t)n_nodes * 4;
        int* rp  = (int*)(base + off2); off2 += (size_t)(n_nodes + 1) * 4;
        int* cs  = (int*)(base + off2); off2 += (size_t)nchunks * 4;
        if (off2 > ws_size) {
            hipMemsetAsync(d_out, 0, (size_t)out_size * sizeof(float), stream);
            spmm_atomic_kernel<<<2048, 256, 0, stream>>>(row, col, vals, embeds, out, n_edges);
            return;
        }
        hipMemsetAsync(rc, 0, (size_t)n_nodes * 2 * sizeof(int), stream);
        hist_kernel<<<2048, 256, 0, stream>>>(row, rc, n_edges);
        scan1_kernel<<<nchunks, SCAN_BLOCK, 0, stream>>>(rc, rp, cs, n_nodes);
        scan2_kernel<<<1, 64, 0, stream>>>(cs, nchunks);
        scan3_kernel<<<(n_nodes + 256) / 256, 256, 0, stream>>>(rp, cs, n_nodes, n_edges);
        scatter_kernel<<<2048, 256, 0, stream>>>(row, col, vals, rp, rf, s_cv, n_edges);
        spmm_csr_kernel<<<4096, 256, 0, stream>>>(rp, s_cv, embeds, out, n_nodes);
        return;
    }

    uint2* tmp;
    unsigned short* embeds16;
    int *bptr, *bfill;

    const int part_blocks = (n_edges + PART_TILE - 1) / PART_TILE;

    if (padded_ok) {
        tmp = tmpP; embeds16 = emb16P; bptr = bptrP; bfill = bfillP;
        bucket_init_padded_kernel<<<(nb + 255) / 256, 256, 0, stream>>>(bptr, bfill, nb, cap_b);
    } else {
        tmp = tmpS; embeds16 = emb16S; bptr = bptrS; bfill = bfillS;
        hipMemsetAsync(bcntS, 0, (size_t)(nb + 1) * sizeof(int), stream);
        bucket_hist_kernel<<<512, 256, 0, stream>>>(row, bcntS, n_edges, nb);
        bucket_scan_kernel<<<1, 1024, 0, stream>>>(bcntS, bptr, bfill, nb);
    }

    partition_kernel<<<part_blocks, 256, 0, stream>>>(row, col, vals, bfill, tmp, n_edges, nb);

    const int n4 = n_nodes * D_FEAT / 4;
    convert_kernel<<<4096, 256, 0, stream>>>(embeds, embeds16, n4);

    // static grid: one block per bucket
    spmm_bucket_sorted_kernel<<<nb, 1024, 0, stream>>>(tmp, bptr, bfill, embeds16, out, n_nodes);
}

// Round 15
// 198.883 us; speedup vs baseline: 1.7182x; 1.0484x over previous
//
#include <hip/hip_runtime.h>
#include <hip/hip_fp16.h>

#define D_FEAT 128

constexpr int SCAN_BLOCK = 256;
constexpr int SCAN_ITEMS = 8;
constexpr int SCAN_CHUNK = SCAN_BLOCK * SCAN_ITEMS;

constexpr int BUCKET_SHIFT = 7;      // 128 rows per bucket
constexpr int TILE_ROWS = 1 << BUCKET_SHIFT;
constexpr int NB_MAX = 1024;
constexpr int PART_TILE = 4096;      // 782 partition blocks @ 3.2M edges
constexpr int CAP = 6144;            // staged edges per batch (48 KB LDS)
constexpr int NKEY = 512;            // 4 col-slices x 128 rows

// ---------------- fallback (round-1) atomic kernel ----------------
__global__ void __launch_bounds__(256) spmm_atomic_kernel(
    const int* __restrict__ row, const int* __restrict__ col,
    const float* __restrict__ vals, const float* __restrict__ embeds,
    float* __restrict__ out, int n_edges)
{
    const int lane = threadIdx.x & 63;
    const int wave_in_block = threadIdx.x >> 6;
    const int waves_per_block = blockDim.x >> 6;
    const int n_waves = gridDim.x * waves_per_block;
    for (int e = blockIdx.x * waves_per_block + wave_in_block; e < n_edges; e += n_waves) {
        const int r = row[e];
        const int c = col[e];
        const float v = vals[e];
        const float2 emb = *reinterpret_cast<const float2*>(&embeds[(size_t)c * D_FEAT + lane * 2]);
        float* o = &out[(size_t)r * D_FEAT + lane * 2];
        atomicAdd(o, emb.x * v);
        atomicAdd(o + 1, emb.y * v);
    }
}

// ================= fast path =================

// LDS-privatized bucket histogram (scanned mode only)
__global__ void __launch_bounds__(256) bucket_hist_kernel(
    const int* __restrict__ row, int* __restrict__ bucket_counts, int n_edges, int nb)
{
    __shared__ int cnt[NB_MAX];
    for (int b = threadIdx.x; b < nb; b += 256) cnt[b] = 0;
    __syncthreads();
    const int i = blockIdx.x * blockDim.x + threadIdx.x;
    const int stride = gridDim.x * blockDim.x;
    const int n4 = n_edges >> 2;
    for (int k = i; k < n4; k += stride) {
        int4 r4 = reinterpret_cast<const int4*>(row)[k];
        atomicAdd(&cnt[r4.x >> BUCKET_SHIFT], 1);
        atomicAdd(&cnt[r4.y >> BUCKET_SHIFT], 1);
        atomicAdd(&cnt[r4.z >> BUCKET_SHIFT], 1);
        atomicAdd(&cnt[r4.w >> BUCKET_SHIFT], 1);
    }
    for (int k = (n4 << 2) + i; k < n_edges; k += stride)
        atomicAdd(&cnt[row[k] >> BUCKET_SHIFT], 1);
    __syncthreads();
    for (int b = threadIdx.x; b < nb; b += 256) {
        int c = cnt[b];
        if (c) atomicAdd(&bucket_counts[b], c);
    }
}

// scanned mode: one block scans bucket counts -> bucket_ptr (excl) + bucket_fill
__global__ void __launch_bounds__(1024) bucket_scan_kernel(
    const int* __restrict__ bucket_counts, int* __restrict__ bucket_ptr,
    int* __restrict__ bucket_fill, int nb)
{
    __shared__ int lds[1024];
    const int t = threadIdx.x;
    lds[t] = (t < nb) ? bucket_counts[t] : 0;
    __syncthreads();
    for (int off = 1; off < 1024; off <<= 1) {
        int x = (t >= off) ? lds[t - off] : 0;
        __syncthreads();
        lds[t] += x;
        __syncthreads();
    }
    const int excl = (t == 0) ? 0 : lds[t - 1];
    if (t <= nb) bucket_ptr[t] = excl;
    if (t < nb)  bucket_fill[t] = excl;
}

// padded mode: fixed-stride bucket bases, no hist/scan needed
__global__ void __launch_bounds__(256) bucket_init_padded_kernel(
    int* __restrict__ bucket_ptr, int* __restrict__ bucket_fill, int nb, int cap_b)
{
    int b = blockIdx.x * blockDim.x + threadIdx.x;
    if (b < nb) {
        bucket_ptr[b]  = b * cap_b;
        bucket_fill[b] = b * cap_b;
    }
}

// partition edges into 128-row buckets; payload (row_local<<17 | col, half2{v,v})
__global__ void __launch_bounds__(256) partition_kernel(
    const int* __restrict__ row, const int* __restrict__ col, const float* __restrict__ vals,
    int* __restrict__ bucket_fill, uint2* __restrict__ tmp, int n_edges, int nb)
{
    __shared__ int cnt[NB_MAX];
    __shared__ int start[NB_MAX];
    const int tid = threadIdx.x;
    const int base = blockIdx.x * PART_TILE;

    for (int b = tid; b < NB_MAX; b += 256) cnt[b] = 0;
    __syncthreads();

    // count pass, int4-vectorized (PART_TILE multiple of 1024)
    #pragma unroll
    for (int k = 0; k < PART_TILE / 1024; ++k) {
        int idx = (base >> 2) + k * 256 + tid;          // int4 index
        if (idx * 4 + 3 < n_edges) {
            int4 r4 = reinterpret_cast<const int4*>(row)[idx];
            atomicAdd(&cnt[r4.x >> BUCKET_SHIFT], 1);
            atomicAdd(&cnt[r4.y >> BUCKET_SHIFT], 1);
            atomicAdd(&cnt[r4.z >> BUCKET_SHIFT], 1);
            atomicAdd(&cnt[r4.w >> BUCKET_SHIFT], 1);
        } else {
            for (int j = 0; j < 4; ++j) {
                int e = idx * 4 + j;
                if (e < n_edges) atomicAdd(&cnt[row[e] >> BUCKET_SHIFT], 1);
            }
        }
    }
    __syncthreads();

    for (int b = tid; b < nb; b += 256) {
        int c = cnt[b];
        if (c > 0) start[b] = atomicAdd(&bucket_fill[b], c);
    }
    __syncthreads();

    // scatter pass, int4/float4-vectorized
    #pragma unroll
    for (int k = 0; k < PART_TILE / 1024; ++k) {
        int idx = (base >> 2) + k * 256 + tid;
        if (idx * 4 + 3 < n_edges) {
            int4  r4 = reinterpret_cast<const int4*>(row)[idx];
            int4  c4 = reinterpret_cast<const int4*>(col)[idx];
            float4 v4 = reinterpret_cast<const float4*>(vals)[idx];
            const int rs[4]   = {r4.x, r4.y, r4.z, r4.w};
            const int cs[4]   = {c4.x, c4.y, c4.z, c4.w};
            const float vs[4] = {v4.x, v4.y, v4.z, v4.w};
            #pragma unroll
            for (int j = 0; j < 4; ++j) {
                int r = rs[j];
                int b = r >> BUCKET_SHIFT;
                int slot = atomicSub(&cnt[b], 1) - 1;
                unsigned hb = (unsigned)__half_as_ushort(__float2half(vs[j]));
                uint2 p;
                p.x = ((unsigned)(r & (TILE_ROWS - 1)) << 17) | (unsigned)cs[j];
                p.y = hb | (hb << 16);
                tmp[start[b] + slot] = p;
            }
        } else {
            for (int j = 0; j < 4; ++j) {
                int e = idx * 4 + j;
                if (e < n_edges) {
                    int r = row[e];
                    int b = r >> BUCKET_SHIFT;
                    int slot = atomicSub(&cnt[b], 1) - 1;
                    unsigned hb = (unsigned)__half_as_ushort(__float2half(vals[e]));
                    uint2 p;
                    p.x = ((unsigned)(r & (TILE_ROWS - 1)) << 17) | (unsigned)col[e];
                    p.y = hb | (hb << 16);
                    tmp[start[b] + slot] = p;
                }
            }
        }
    }
}

// ---------------- embeds f32 -> f16 ----------------
__global__ void __launch_bounds__(256) convert_kernel(
    const float* __restrict__ embeds, unsigned short* __restrict__ out16, int n4)
{
    int i = blockIdx.x * blockDim.x + threadIdx.x;
    int stride = gridDim.x * blockDim.x;
    for (; i < n4; i += stride) {
        float4 f = *reinterpret_cast<const float4*>(&embeds[(size_t)i * 4]);
        ushort4 o;
        o.x = __half_as_ushort(__float2half(f.x));
        o.y = __half_as_ushort(__float2half(f.y));
        o.z = __half_as_ushort(__float2half(f.z));
        o.w = __half_as_ushort(__float2half(f.w));
        *reinterpret_cast<ushort4*>(&out16[(size_t)i * 4]) = o;
    }
}

__device__ __forceinline__ __half2 u2h2(unsigned u)
{
    return *reinterpret_cast<__half2*>(&u);
}

// ---------------- fused sort+SpMM: 4-slice sort key ----------------
// Sort key = slice(col bits 15-16)<<7 | row_local -> 512 keys. Consume is
// slice-major: all resident blocks sweep embeds16 in 8.4MB quarters in phase
// (vs 16MB halves in round 14). Segments average ~8 edges = one unroll-8
// iteration. Wave-0 shfl scan at 8 elems/lane.
__global__ void __launch_bounds__(1024, 8) spmm_bucket_sorted_kernel(
    const uint2* __restrict__ tmp, const int* __restrict__ bucket_ptr,
    const int* __restrict__ bucket_fill,
    const unsigned short* __restrict__ embeds16, float* __restrict__ out, int n_nodes)
{
    __shared__ uint2 sedge[CAP];          // 48 KB
    __shared__ int cnt[NKEY];             // 2 KB
    __shared__ int rstart[NKEY];          // 2 KB
    __shared__ int rcur[NKEY];            // 2 KB

    const int b = blockIdx.x;
    const int lo = bucket_ptr[b];
    const int hi = bucket_fill[b];        // final fill = base + count (both modes)
    const int t = threadIdx.x;
    const int lane = t & 63;
    const int h = lane >> 5;              // half-wave id (0/1)
    const int lq = lane & 31;             // lane within half; owns feats lq*4..+3
    const int w = t >> 6;                 // wave 0..15, owns rows 8w..8w+7

    __half2 acc[16];                      // [2*rr] = feats lq*4..+1, [2*rr+1] = +2..+3
    #pragma unroll
    for (int i = 0; i < 16; ++i) acc[i] = __float2half2_rn(0.f);

    for (int cur = lo; cur < hi; cur += CAP) {
        const int bcount = min(CAP, hi - cur);

        // stage edges into registers (coalesced), CAP/1024 = 6 per thread
        uint2 e[6];
        #pragma unroll
        for (int k = 0; k < 6; ++k) {
            int idx = t + k * 1024;
            if (idx < bcount) e[k] = tmp[cur + idx];
        }
        if (t < NKEY) { cnt[t] = 0; rcur[t] = 0; }
        __syncthreads();

        // per-key count: key = slice(col bits 15-16)<<7 | row_local
        #pragma unroll
        for (int k = 0; k < 6; ++k) {
            int idx = t + k * 1024;
            if (idx < bcount) {
                unsigned px = e[k].x;
                int key = (int)(((px >> 15) & 3u) << 7) | (int)((px >> 17) & (TILE_ROWS - 1));
                atomicAdd(&cnt[key], 1);
            }
        }
        __syncthreads();

        // wave 0: exclusive scan of cnt[512], 8 elems/lane, shfl_up (no barriers)
        if (w == 0) {
            int c[8], s = 0;
            #pragma unroll
            for (int k = 0; k < 8; ++k) { c[k] = cnt[8 * lane + k]; s += c[k]; }
            int inc = s;
            #pragma unroll
            for (int off = 1; off < 64; off <<= 1) {
                int x = __shfl_up(inc, off);
                if (lane >= off) inc += x;
            }
            int excl = inc - s;
            #pragma unroll
            for (int k = 0; k < 8; ++k) { rstart[8 * lane + k] = excl; excl += c[k]; }
        }
        __syncthreads();

        // scatter key-sorted into sedge
        #pragma unroll
        for (int k = 0; k < 6; ++k) {
            int idx = t + k * 1024;
            if (idx < bcount) {
                unsigned px = e[k].x;
                int key = (int)(((px >> 15) & 3u) << 7) | (int)((px >> 17) & (TILE_ROWS - 1));
                int pos = rstart[key] + atomicAdd(&rcur[key], 1);
                sedge[pos] = uint2{px & 0x1FFFFu, e[k].y};
            }
        }
        __syncthreads();

        // consume slice-major: wave w rows 8w..8w+7, slices 0..3 in phase
        for (int s = 0; s < 4; ++s) {
            #pragma unroll
            for (int rr = 0; rr < 8; ++rr) {
                const int key = (s << 7) | (w * 8 + rr);
                const int js = rstart[key];
                const int je = js + cnt[key];
                int j = js;
                for (; j + 7 < je; j += 8) {
                    uint2 q0 = sedge[j + 0 + h];
                    uint2 q1 = sedge[j + 2 + h];
                    uint2 q2 = sedge[j + 4 + h];
                    uint2 q3 = sedge[j + 6 + h];
                    uint2 u0 = *reinterpret_cast<const uint2*>(&embeds16[((size_t)q0.x << 7) + lq * 4]);
                    uint2 u1 = *reinterpret_cast<const uint2*>(&embeds16[((size_t)q1.x << 7) + lq * 4]);
                    uint2 u2 = *reinterpret_cast<const uint2*>(&embeds16[((size_t)q2.x << 7) + lq * 4]);
                    uint2 u3 = *reinterpret_cast<const uint2*>(&embeds16[((size_t)q3.x << 7) + lq * 4]);
                    acc[2*rr]   = __hfma2(u2h2(q0.y), u2h2(u0.x), acc[2*rr]);
                    acc[2*rr+1] = __hfma2(u2h2(q0.y), u2h2(u0.y), acc[2*rr+1]);
                    acc[2*rr]   = __hfma2(u2h2(q1.y), u2h2(u1.x), acc[2*rr]);
                    acc[2*rr+1] = __hfma2(u2h2(q1.y), u2h2(u1.y), acc[2*rr+1]);
                    acc[2*rr]   = __hfma2(u2h2(q2.y), u2h2(u2.x), acc[2*rr]);
                    acc[2*rr+1] = __hfma2(u2h2(q2.y), u2h2(u2.y), acc[2*rr+1]);
                    acc[2*rr]   = __hfma2(u2h2(q3.y), u2h2(u3.x), acc[2*rr]);
                    acc[2*rr+1] = __hfma2(u2h2(q3.y), u2h2(u3.y), acc[2*rr+1]);
                }
                for (; j + 1 < je; j += 2) {
                    uint2 q = sedge[j + h];
                    uint2 u = *reinterpret_cast<const uint2*>(&embeds16[((size_t)q.x << 7) + lq * 4]);
                    acc[2*rr]   = __hfma2(u2h2(q.y), u2h2(u.x), acc[2*rr]);
                    acc[2*rr+1] = __hfma2(u2h2(q.y), u2h2(u.y), acc[2*rr+1]);
                }
                if (j < je && h == 0) {      // single leftover edge: half 0 only
                    uint2 q = sedge[j];
                    uint2 u = *reinterpret_cast<const uint2*>(&embeds16[((size_t)q.x << 7) + lq * 4]);
                    acc[2*rr]   = __hfma2(u2h2(q.y), u2h2(u.x), acc[2*rr]);
                    acc[2*rr+1] = __hfma2(u2h2(q.y), u2h2(u.y), acc[2*rr+1]);
                }
            }
        }
        __syncthreads();   // protect sedge before next batch
    }

    // convert to f32, merge halves (disjoint edge subsets), write
    float4 facc[8];
    #pragma unroll
    for (int rr = 0; rr < 8; ++rr) {
        float2 a = __half22float2(acc[2*rr]);
        float2 bq = __half22float2(acc[2*rr+1]);
        facc[rr] = float4{a.x, a.y, bq.x, bq.y};
        facc[rr].x += __shfl_xor(facc[rr].x, 32);
        facc[rr].y += __shfl_xor(facc[rr].y, 32);
        facc[rr].z += __shfl_xor(facc[rr].z, 32);
        facc[rr].w += __shfl_xor(facc[rr].w, 32);
    }

    // half h writes rows w*8 + k + 4h (static indices + cndmask select)
    const int rbase = b << BUCKET_SHIFT;
    #pragma unroll
    for (int k = 0; k < 4; ++k) {
        float4 a0 = facc[k];
        float4 a1 = facc[k + 4];
        float4 vv;
        vv.x = h ? a1.x : a0.x;
        vv.y = h ? a1.y : a0.y;
        vv.z = h ? a1.z : a0.z;
        vv.w = h ? a1.w : a0.w;
        int r = rbase + w * 8 + k + 4 * h;
        if (r < n_nodes)
            *reinterpret_cast<float4*>(&out[(size_t)r * D_FEAT + lq * 4]) = vv;
    }
}

// ================= round-2 fallback pieces =================
__global__ void hist_kernel(const int* __restrict__ row, int* __restrict__ counts, int n)
{
    int i = blockIdx.x * blockDim.x + threadIdx.x;
    int stride = gridDim.x * blockDim.x;
    for (; i < n; i += stride) atomicAdd(&counts[row[i]], 1);
}

__global__ void __launch_bounds__(SCAN_BLOCK) scan1_kernel(
    const int* __restrict__ counts, int* __restrict__ scan_out,
    int* __restrict__ chunk_sums, int n)
{
    __shared__ int lds[SCAN_BLOCK];
    const int chunk = blockIdx.x;
    const int base = chunk * SCAN_CHUNK;
    const int tbase = base + threadIdx.x * SCAN_ITEMS;

    int pref[SCAN_ITEMS];
    int tsum = 0;
    for (int k = 0; k < SCAN_ITEMS; ++k) {
        int idx = tbase + k;
        int v = (idx < n) ? counts[idx] : 0;
        pref[k] = tsum;
        tsum += v;
    }
    lds[threadIdx.x] = tsum;
    __syncthreads();
    for (int off = 1; off < SCAN_BLOCK; off <<= 1) {
        int v = (threadIdx.x >= off) ? lds[threadIdx.x - off] : 0;
        __syncthreads();
        lds[threadIdx.x] += v;
        __syncthreads();
    }
    const int texcl = (threadIdx.x == 0) ? 0 : lds[threadIdx.x - 1];
    for (int k = 0; k < SCAN_ITEMS; ++k) {
        int idx = tbase + k;
        if (idx < n) scan_out[idx] = texcl + pref[k];
    }
    if (threadIdx.x == SCAN_BLOCK - 1) chunk_sums[chunk] = lds[SCAN_BLOCK - 1];
}

__global__ void scan2_kernel(int* chunk_sums, int nchunks)
{
    if (blockIdx.x == 0 && threadIdx.x == 0) {
        int acc = 0;
        for (int i = 0; i < nchunks; ++i) { int v = chunk_sums[i]; chunk_sums[i] = acc; acc += v; }
    }
}

__global__ void scan3_kernel(int* __restrict__ row_ptr, const int* __restrict__ chunk_sums,
                             int n, int n_edges)
{
    int i = blockIdx.x * blockDim.x + threadIdx.x;
    if (i < n) row_ptr[i] += chunk_sums[i / SCAN_CHUNK];
    if (i == 0) row_ptr[n] = n_edges;
}

__global__ void scatter_kernel(const int* __restrict__ row, const int* __restrict__ col,
                               const float* __restrict__ vals,
                               const int* __restrict__ row_ptr, int* __restrict__ row_fill,
                               uint2* __restrict__ sorted_cv, int n_edges)
{
    int i = blockIdx.x * blockDim.x + threadIdx.x;
    int stride = gridDim.x * blockDim.x;
    for (; i < n_edges; i += stride) {
        int r = row[i];
        int pos = row_ptr[r] + atomicAdd(&row_fill[r], 1);
        uint2 cv;
        cv.x = (unsigned)col[i];
        cv.y = __float_as_uint(vals[i]);
        sorted_cv[pos] = cv;
    }
}

__global__ void __launch_bounds__(256) spmm_csr_kernel(
    const int* __restrict__ row_ptr, const uint2* __restrict__ sorted_cv,
    const float* __restrict__ embeds, float* __restrict__ out, int n_rows)
{
    const int lane = threadIdx.x & 63;
    const int wid = (blockIdx.x * blockDim.x + threadIdx.x) >> 6;
    const int n_waves = (gridDim.x * blockDim.x) >> 6;

    for (int r = wid; r < n_rows; r += n_waves) {
        const int start = row_ptr[r];
        const int end   = row_ptr[r + 1];
        float2 acc = {0.f, 0.f};
        for (int j = start; j < end; ++j) {
            uint2 cv = sorted_cv[j];
            const float2 e = *reinterpret_cast<const float2*>(&embeds[(size_t)cv.x * D_FEAT + lane * 2]);
            const float v = __uint_as_float(cv.y);
            acc.x += v * e.x;
            acc.y += v * e.y;
        }
        *reinterpret_cast<float2*>(&out[(size_t)r * D_FEAT + lane * 2]) = acc;
    }
}

extern "C" void kernel_launch(void* const* d_in, const int* in_sizes, int n_in,
                              void* d_out, int out_size, void* d_ws, size_t ws_size,
                              hipStream_t stream) {
    const int*   row    = (const int*)d_in[0];
    const int*   col    = (const int*)d_in[1];
    const float* vals   = (const float*)d_in[2];
    const float* embeds = (const float*)d_in[3];
    float*       out    = (float*)d_out;

    const int n_edges = in_sizes[0];
    const int n_nodes = in_sizes[3] / D_FEAT;
    const int nchunks = (n_nodes + SCAN_CHUNK - 1) / SCAN_CHUNK;
    const int nb = (n_nodes + TILE_ROWS - 1) >> BUCKET_SHIFT;

    // padded bucket stride: avg + 25% + 256 (>=16 sigma for Binomial bucket sizes)
    const int avg = n_edges / (nb > 0 ? nb : 1);
    const int cap_b = avg + avg / 4 + 256;

    char* base = (char*)d_ws;

    // padded layout (no hist/scan)
    size_t offP = 0;
    uint2* tmpP           = (uint2*)(base + offP);             offP += ((size_t)nb * cap_b * 8 + 255) & ~(size_t)255;
    unsigned short* emb16P = (unsigned short*)(base + offP);   offP += ((size_t)n_nodes * D_FEAT * 2 + 255) & ~(size_t)255;
    int* bptrP            = (int*)(base + offP);               offP += (size_t)(nb + 1) * 4;
    int* bfillP           = (int*)(base + offP);               offP += (size_t)(nb + 1) * 4;

    // scanned layout (exact tmp)
    size_t offS = 0;
    uint2* tmpS           = (uint2*)(base + offS);             offS += ((size_t)n_edges * 8 + 255) & ~(size_t)255;
    unsigned short* emb16S = (unsigned short*)(base + offS);   offS += ((size_t)n_nodes * D_FEAT * 2 + 255) & ~(size_t)255;
    int* bcntS            = (int*)(base + offS);               offS += (size_t)(nb + 1) * 4;
    int* bptrS            = (int*)(base + offS);               offS += (size_t)(nb + 1) * 4;
    int* bfillS           = (int*)(base + offS);               offS += (size_t)(nb + 1) * 4;

    const bool common_ok = (nb <= 1023) && (n_nodes < (1 << 17));
    const bool padded_ok  = common_ok && (offP <= ws_size);
    const bool scanned_ok = common_ok && (offS <= ws_size);

    if (!padded_ok && !scanned_ok) {
        // round-2 fallback layout
        size_t off2 = 0;
        uint2* s_cv = (uint2*)(base + off2); off2 += (size_t)n_edges * 8;
        int* rc  = (int*)(base + off2); off2 += (size_t)n_nodes * 4;
        int* rf  = (int*)(base + off2); off2 += (size_t)n_nodes * 4;
        int* rp  = (int*)(base + off2); off2 += (size_t)(n_nodes + 1) * 4;
        int* cs  = (int*)(base + off2); off2 += (size_t)nchunks * 4;
        if (off2 > ws_size) {
            hipMemsetAsync(d_out, 0, (size_t)out_size * sizeof(float), stream);
            spmm_atomic_kernel<<<2048, 256, 0, stream>>>(row, col, vals, embeds, out, n_edges);
            return;
        }
        hipMemsetAsync(rc, 0, (size_t)n_nodes * 2 * sizeof(int), stream);
        hist_kernel<<<2048, 256, 0, stream>>>(row, rc, n_edges);
        scan1_kernel<<<nchunks, SCAN_BLOCK, 0, stream>>>(rc, rp, cs, n_nodes);
        scan2_kernel<<<1, 64, 0, stream>>>(cs, nchunks);
        scan3_kernel<<<(n_nodes + 256) / 256, 256, 0, stream>>>(rp, cs, n_nodes, n_edges);
        scatter_kernel<<<2048, 256, 0, stream>>>(row, col, vals, rp, rf, s_cv, n_edges);
        spmm_csr_kernel<<<4096, 256, 0, stream>>>(rp, s_cv, embeds, out, n_nodes);
        return;
    }

    uint2* tmp;
    unsigned short* embeds16;
    int *bptr, *bfill;

    const int part_blocks = (n_edges + PART_TILE - 1) / PART_TILE;

    if (padded_ok) {
        tmp = tmpP; embeds16 = emb16P; bptr = bptrP; bfill = bfillP;
        bucket_init_padded_kernel<<<(nb + 255) / 256, 256, 0, stream>>>(bptr, bfill, nb, cap_b);
    } else {
        tmp = tmpS; embeds16 = emb16S; bptr = bptrS; bfill = bfillS;
        hipMemsetAsync(bcntS, 0, (size_t)(nb + 1) * sizeof(int), stream);
        bucket_hist_kernel<<<512, 256, 0, stream>>>(row, bcntS, n_edges, nb);
        bucket_scan_kernel<<<1, 1024, 0, stream>>>(bcntS, bptr, bfill, nb);
    }

    partition_kernel<<<part_blocks, 256, 0, stream>>>(row, col, vals, bfill, tmp, n_edges, nb);

    const int n4 = n_nodes * D_FEAT / 4;
    convert_kernel<<<4096, 256, 0, stream>>>(embeds, embeds16, n4);

    // static grid: one block per bucket
    spmm_bucket_sorted_kernel<<<nb, 1024, 0, stream>>>(tmp, bptr, bfill, embeds16, out, n_nodes);
}